// Round 1
// baseline (4467.587 us; speedup 1.0000x reference)
//
#include <hip/hip_runtime.h>
#include <hip/hip_bf16.h>
#include <cmath>

// Problem constants (HSTU layer): B=2, S=2048, D=1024, H=16, HD=64
#define BB 2
#define SS 2048
#define DD 1024
#define HH 16
#define HDD 64
#define EPS 1e-5f

// ---------------------------------------------------------------------------
// Kernel 1: LayerNorm over last dim (D=1024). One block (256 threads) per row.
// ---------------------------------------------------------------------------
__global__ __launch_bounds__(256) void ln_kernel(
    const float* __restrict__ x, const float* __restrict__ gamma,
    const float* __restrict__ beta, float* __restrict__ xn) {
  int row = blockIdx.x;
  int t = threadIdx.x;
  const float* xr = x + (size_t)row * DD;
  float4 v = *(const float4*)(xr + t * 4);
  float s = v.x + v.y + v.z + v.w;
  float sq = v.x * v.x + v.y * v.y + v.z * v.z + v.w * v.w;
  // wave (64-lane) reduce
  for (int off = 32; off > 0; off >>= 1) {
    s += __shfl_down(s, off, 64);
    sq += __shfl_down(sq, off, 64);
  }
  __shared__ float ls[4], lq[4];
  int wave = t >> 6, lane = t & 63;
  if (lane == 0) { ls[wave] = s; lq[wave] = sq; }
  __syncthreads();
  float tot = ls[0] + ls[1] + ls[2] + ls[3];
  float totq = lq[0] + lq[1] + lq[2] + lq[3];
  float mu = tot * (1.0f / DD);
  float var = totq * (1.0f / DD) - mu * mu;
  float rstd = rsqrtf(var + EPS);
  float4 g = *(const float4*)(gamma + t * 4);
  float4 bt = *(const float4*)(beta + t * 4);
  float4 o;
  o.x = (v.x - mu) * rstd * g.x + bt.x;
  o.y = (v.y - mu) * rstd * g.y + bt.y;
  o.z = (v.z - mu) * rstd * g.z + bt.z;
  o.w = (v.w - mu) * rstd * g.w + bt.w;
  *(float4*)(xn + (size_t)row * DD + t * 4) = o;
}

// ---------------------------------------------------------------------------
// Kernel 2: tiled fp32 GEMM  C[M,N] = epilogue(A (*A2) @ W + bias (+resid))
// M=4096, K=1024 fixed. 64x64 tile, BK=16, 256 threads, 4x4 microtile.
// ACT: 0 none, 1 SiLU.  HAS_A2: elementwise A*A2 on load.  HAS_RES: +resid.
// ---------------------------------------------------------------------------
template <int ACT, bool HAS_A2, bool HAS_RES>
__global__ __launch_bounds__(256) void gemm_fused(
    const float* __restrict__ A, const float* __restrict__ A2,
    const float* __restrict__ W, const float* __restrict__ bias,
    const float* __restrict__ resid, float* __restrict__ C, int N) {
  __shared__ float As[16][64];  // [k][m] (transposed)
  __shared__ float Ws[16][64];  // [k][n]
  const int K = 1024;
  int tid = threadIdx.x;
  int ty = tid >> 4, tx = tid & 15;
  int m0 = blockIdx.y * 64, n0 = blockIdx.x * 64;
  float acc[4][4] = {{0.f}};

  int ar = tid >> 2;             // A-tile row 0..63
  int akc = (tid & 3) * 4;       // A-tile k-col group
  int wk = tid >> 4;             // W-tile k row 0..15
  int wnc = (tid & 15) * 4;      // W-tile n col group

  for (int k0 = 0; k0 < K; k0 += 16) {
    float4 a = *(const float4*)(A + (size_t)(m0 + ar) * K + k0 + akc);
    if (HAS_A2) {
      float4 a2 = *(const float4*)(A2 + (size_t)(m0 + ar) * K + k0 + akc);
      a.x *= a2.x; a.y *= a2.y; a.z *= a2.z; a.w *= a2.w;
    }
    float4 w = *(const float4*)(W + (size_t)(k0 + wk) * N + n0 + wnc);
    As[akc + 0][ar] = a.x;
    As[akc + 1][ar] = a.y;
    As[akc + 2][ar] = a.z;
    As[akc + 3][ar] = a.w;
    *(float4*)&Ws[wk][wnc] = w;
    __syncthreads();
#pragma unroll
    for (int k = 0; k < 16; ++k) {
      float4 av = *(const float4*)&As[k][ty * 4];
      float4 wv = *(const float4*)&Ws[k][tx * 4];
      float av_[4] = {av.x, av.y, av.z, av.w};
      float wv_[4] = {wv.x, wv.y, wv.z, wv.w};
#pragma unroll
      for (int i = 0; i < 4; ++i)
#pragma unroll
        for (int j = 0; j < 4; ++j) acc[i][j] += av_[i] * wv_[j];
    }
    __syncthreads();
  }
  // epilogue
#pragma unroll
  for (int i = 0; i < 4; ++i) {
    int m = m0 + ty * 4 + i;
    int n = n0 + tx * 4;
    float4 bb = *(const float4*)(bias + n);
    float4 c;
    c.x = acc[i][0] + bb.x;
    c.y = acc[i][1] + bb.y;
    c.z = acc[i][2] + bb.z;
    c.w = acc[i][3] + bb.w;
    if (ACT == 1) {  // SiLU
      c.x = c.x / (1.0f + __expf(-c.x));
      c.y = c.y / (1.0f + __expf(-c.y));
      c.z = c.z / (1.0f + __expf(-c.z));
      c.w = c.w / (1.0f + __expf(-c.w));
    }
    if (HAS_RES) {
      float4 rr = *(const float4*)(resid + (size_t)m * N + n);
      c.x += rr.x; c.y += rr.y; c.z += rr.z; c.w += rr.w;
    }
    *(float4*)(C + (size_t)m * N + n) = c;
  }
}

// ---------------------------------------------------------------------------
// Kernel 3: sigmoid attention, causal. One block per (64 q rows, b, h).
// Streaming over 64-key tiles; no softmax normalization needed (sigmoid).
// qkv row layout per token: [3, H, HD] -> q at h*64, k at 1024+h*64, v at 2048+h*64.
// ctx written in [B, S, H*HD] layout (ready for out-GEMM).
// ---------------------------------------------------------------------------
__global__ __launch_bounds__(256) void attn_kernel(
    const float* __restrict__ qkv, const float* __restrict__ rpb,
    float* __restrict__ ctxg) {
  __shared__ float Qt[64][64];  // [d][q]
  __shared__ float Kt[64][64];  // [d][k]
  __shared__ float Vs[64][64];  // [k][d]
  __shared__ float St[64][64];  // [k][q]  (sigmoid scores, transposed)

  int q0 = blockIdx.x * 64;
  int bh = blockIdx.y;
  int b = bh >> 4, h = bh & 15;
  int t = threadIdx.x;
  int ty = t >> 4, tx = t & 15;
  int r = t >> 2;            // 0..63
  int c0 = (t & 3) * 16;     // 0,16,32,48

  size_t base = (size_t)b * SS * 3072 + (size_t)h * 64;

  // load Q tile transposed: Qt[d][q]
  {
    const float* src = qkv + base + (size_t)(q0 + r) * 3072 + c0;
#pragma unroll
    for (int cc = 0; cc < 4; ++cc) {
      float4 v = *(const float4*)(src + cc * 4);
      int c = c0 + cc * 4;
      Qt[c + 0][r] = v.x; Qt[c + 1][r] = v.y;
      Qt[c + 2][r] = v.z; Qt[c + 3][r] = v.w;
    }
  }

  float ctx[4][4] = {{0.f}};
  float hb = rpb[h];
  const float scale = 0.125f;  // HD^-0.5 = 1/8
  int ntiles = (q0 >> 6) + 1;  // causal: key tiles 0..q0/64

  for (int kt = 0; kt < ntiles; ++kt) {
    int k0 = kt * 64;
    __syncthreads();  // protect Kt/Vs (prev iter readers) and Qt (first iter)
    {
      const float* ksrc = qkv + base + 1024 + (size_t)(k0 + r) * 3072 + c0;
      const float* vsrc = qkv + base + 2048 + (size_t)(k0 + r) * 3072 + c0;
#pragma unroll
      for (int cc = 0; cc < 4; ++cc) {
        float4 kv = *(const float4*)(ksrc + cc * 4);
        int c = c0 + cc * 4;
        Kt[c + 0][r] = kv.x; Kt[c + 1][r] = kv.y;
        Kt[c + 2][r] = kv.z; Kt[c + 3][r] = kv.w;
        float4 vv = *(const float4*)(vsrc + cc * 4);
        *(float4*)&Vs[r][c] = vv;
      }
    }
    __syncthreads();
    // scores: sc[i][j] = sum_d Q[q0+ty*4+i][d] * K[k0+tx*4+j][d]
    float sc[4][4] = {{0.f}};
#pragma unroll
    for (int d = 0; d < 64; ++d) {
      float4 qv = *(const float4*)&Qt[d][ty * 4];
      float4 kv = *(const float4*)&Kt[d][tx * 4];
      float q_[4] = {qv.x, qv.y, qv.z, qv.w};
      float k_[4] = {kv.x, kv.y, kv.z, kv.w};
#pragma unroll
      for (int i = 0; i < 4; ++i)
#pragma unroll
        for (int j = 0; j < 4; ++j) sc[i][j] += q_[i] * k_[j];
    }
    // sigmoid + causal mask, store transposed St[k][q]
#pragma unroll
    for (int j = 0; j < 4; ++j) {
      int kk = k0 + tx * 4 + j;
#pragma unroll
      for (int i = 0; i < 4; ++i) {
        int qq = q0 + ty * 4 + i;
        float sv = sc[i][j] * scale + hb;
        float p = (kk <= qq) ? 1.0f / (1.0f + __expf(-sv)) : 0.0f;
        St[tx * 4 + j][ty * 4 + i] = p;
      }
    }
    __syncthreads();
    // ctx[i][j] += sum_key St[key][q] * Vs[key][d]
#pragma unroll
    for (int key = 0; key < 64; ++key) {
      float4 sv = *(const float4*)&St[key][ty * 4];
      float4 vv = *(const float4*)&Vs[key][tx * 4];
      float s_[4] = {sv.x, sv.y, sv.z, sv.w};
      float v_[4] = {vv.x, vv.y, vv.z, vv.w};
#pragma unroll
      for (int i = 0; i < 4; ++i)
#pragma unroll
        for (int j = 0; j < 4; ++j) ctx[i][j] += s_[i] * v_[j];
    }
  }
  // write ctx in [B,S,D] layout at column h*64
#pragma unroll
  for (int i = 0; i < 4; ++i) {
    float4 o = {ctx[i][0], ctx[i][1], ctx[i][2], ctx[i][3]};
    *(float4*)(ctxg + (size_t)(b * SS + q0 + ty * 4 + i) * DD + h * 64 + tx * 4) = o;
  }
}

// ---------------------------------------------------------------------------
extern "C" void kernel_launch(void* const* d_in, const int* in_sizes, int n_in,
                              void* d_out, int out_size, void* d_ws, size_t ws_size,
                              hipStream_t stream) {
  const float* x      = (const float*)d_in[0];
  // d_in[1] = attention_mask (causal tril) — computed analytically, not read
  const float* gamma  = (const float*)d_in[2];
  const float* beta   = (const float*)d_in[3];
  const float* w_qkv  = (const float*)d_in[4];
  const float* b_qkv  = (const float*)d_in[5];
  const float* w_gate = (const float*)d_in[6];
  const float* b_gate = (const float*)d_in[7];
  const float* w_out  = (const float*)d_in[8];
  const float* b_out  = (const float*)d_in[9];
  const float* rpb    = (const float*)d_in[10];
  float* out = (float*)d_out;

  float* xn  = (float*)d_ws;            // 4096*1024
  float* qkv = xn + 4194304;            // 4096*3072
  float* u   = qkv + 12582912;          // 4096*1024
  float* ctx = u + 4194304;             // 4096*1024

  // 1. LayerNorm
  ln_kernel<<<BB * SS, 256, 0, stream>>>(x, gamma, beta, xn);
  // 2. QKV projection: [4096,1024] @ [1024,3072]
  gemm_fused<0, false, false><<<dim3(3072 / 64, 4096 / 64), 256, 0, stream>>>(
      xn, nullptr, w_qkv, b_qkv, nullptr, qkv, 3072);
  // 3. Gate projection + SiLU: [4096,1024] @ [1024,1024]
  gemm_fused<1, false, false><<<dim3(1024 / 64, 4096 / 64), 256, 0, stream>>>(
      xn, nullptr, w_gate, b_gate, nullptr, u, 1024);
  // 4. Sigmoid attention (causal), ctx in [B,S,D] layout
  attn_kernel<<<dim3(SS / 64, BB * HH), 256, 0, stream>>>(qkv, rpb, ctx);
  // 5. Output projection: (ctx * u) @ w_out + b_out + x
  gemm_fused<0, true, true><<<dim3(1024 / 64, 4096 / 64), 256, 0, stream>>>(
      ctx, u, w_out, b_out, x, out, 1024);
}

// Round 2
// 813.885 us; speedup vs baseline: 5.4892x; 5.4892x over previous
//
#include <hip/hip_runtime.h>
#include <hip/hip_bf16.h>
#include <cmath>

// Problem constants (HSTU layer): B=2, S=2048, D=1024, H=16, HD=64
#define BB 2
#define SS 2048
#define DD 1024
#define HH 16
#define HDD 64
#define EPS 1e-5f

typedef __attribute__((ext_vector_type(8))) short short8;   // 8 bf16 (4 VGPRs)
typedef __attribute__((ext_vector_type(4))) float f32x4;    // 4 fp32 acc

__device__ inline unsigned short f2bf(float f) {
  union { float f; unsigned int u; } v; v.f = f;
  unsigned int u = v.u;
  unsigned int r = (u + 0x7FFFu + ((u >> 16) & 1u)) >> 16;  // RNE
  return (unsigned short)r;
}

// ---------------------------------------------------------------------------
// Kernel 1: LayerNorm over last dim (D=1024). One block (256 threads) per row.
// ---------------------------------------------------------------------------
__global__ __launch_bounds__(256) void ln_kernel(
    const float* __restrict__ x, const float* __restrict__ gamma,
    const float* __restrict__ beta, float* __restrict__ xn) {
  int row = blockIdx.x;
  int t = threadIdx.x;
  const float* xr = x + (size_t)row * DD;
  float4 v = *(const float4*)(xr + t * 4);
  float s = v.x + v.y + v.z + v.w;
  float sq = v.x * v.x + v.y * v.y + v.z * v.z + v.w * v.w;
  for (int off = 32; off > 0; off >>= 1) {
    s += __shfl_down(s, off, 64);
    sq += __shfl_down(sq, off, 64);
  }
  __shared__ float ls[4], lq[4];
  int wave = t >> 6, lane = t & 63;
  if (lane == 0) { ls[wave] = s; lq[wave] = sq; }
  __syncthreads();
  float tot = ls[0] + ls[1] + ls[2] + ls[3];
  float totq = lq[0] + lq[1] + lq[2] + lq[3];
  float mu = tot * (1.0f / DD);
  float var = totq * (1.0f / DD) - mu * mu;
  float rstd = rsqrtf(var + EPS);
  float4 g = *(const float4*)(gamma + t * 4);
  float4 bt = *(const float4*)(beta + t * 4);
  float4 o;
  o.x = (v.x - mu) * rstd * g.x + bt.x;
  o.y = (v.y - mu) * rstd * g.y + bt.y;
  o.z = (v.z - mu) * rstd * g.z + bt.z;
  o.w = (v.w - mu) * rstd * g.w + bt.w;
  *(float4*)(xn + (size_t)row * DD + t * 4) = o;
}

// ---------------------------------------------------------------------------
// Kernel 2: tiled fp32 GEMM  C[M,N] = epilogue(A (*A2) @ W + bias (+resid))
// M=4096, K=1024 fixed. 64x64 tile, BK=16, 256 threads, 4x4 microtile.
// ACT: 0 none, 1 SiLU.  HAS_A2: elementwise A*A2.  HAS_RES: +resid.
// OUT_BF16: write bf16 instead of fp32.
// ---------------------------------------------------------------------------
template <int ACT, bool HAS_A2, bool HAS_RES, bool OUT_BF16>
__global__ __launch_bounds__(256) void gemm_fused(
    const float* __restrict__ A, const float* __restrict__ A2,
    const float* __restrict__ W, const float* __restrict__ bias,
    const float* __restrict__ resid, void* __restrict__ Cv, int N) {
  __shared__ float As[16][64];  // [k][m]
  __shared__ float Ws[16][64];  // [k][n]
  const int K = 1024;
  int tid = threadIdx.x;
  int ty = tid >> 4, tx = tid & 15;
  int m0 = blockIdx.y * 64, n0 = blockIdx.x * 64;
  float acc[4][4] = {{0.f}};

  int ar = tid >> 2;
  int akc = (tid & 3) * 4;
  int wk = tid >> 4;
  int wnc = (tid & 15) * 4;

  for (int k0 = 0; k0 < K; k0 += 16) {
    float4 a = *(const float4*)(A + (size_t)(m0 + ar) * K + k0 + akc);
    if (HAS_A2) {
      float4 a2 = *(const float4*)(A2 + (size_t)(m0 + ar) * K + k0 + akc);
      a.x *= a2.x; a.y *= a2.y; a.z *= a2.z; a.w *= a2.w;
    }
    float4 w = *(const float4*)(W + (size_t)(k0 + wk) * N + n0 + wnc);
    As[akc + 0][ar] = a.x;
    As[akc + 1][ar] = a.y;
    As[akc + 2][ar] = a.z;
    As[akc + 3][ar] = a.w;
    *(float4*)&Ws[wk][wnc] = w;
    __syncthreads();
#pragma unroll
    for (int k = 0; k < 16; ++k) {
      float4 av = *(const float4*)&As[k][ty * 4];
      float4 wv = *(const float4*)&Ws[k][tx * 4];
      float av_[4] = {av.x, av.y, av.z, av.w};
      float wv_[4] = {wv.x, wv.y, wv.z, wv.w};
#pragma unroll
      for (int i = 0; i < 4; ++i)
#pragma unroll
        for (int j = 0; j < 4; ++j) acc[i][j] += av_[i] * wv_[j];
    }
    __syncthreads();
  }
#pragma unroll
  for (int i = 0; i < 4; ++i) {
    int m = m0 + ty * 4 + i;
    int n = n0 + tx * 4;
    float4 bb = *(const float4*)(bias + n);
    float4 c;
    c.x = acc[i][0] + bb.x;
    c.y = acc[i][1] + bb.y;
    c.z = acc[i][2] + bb.z;
    c.w = acc[i][3] + bb.w;
    if (ACT == 1) {
      c.x = c.x / (1.0f + __expf(-c.x));
      c.y = c.y / (1.0f + __expf(-c.y));
      c.z = c.z / (1.0f + __expf(-c.z));
      c.w = c.w / (1.0f + __expf(-c.w));
    }
    if (HAS_RES) {
      float4 rr = *(const float4*)(resid + (size_t)m * N + n);
      c.x += rr.x; c.y += rr.y; c.z += rr.z; c.w += rr.w;
    }
    if (OUT_BF16) {
      unsigned short* C = (unsigned short*)Cv;
      ushort4 o;
      o.x = f2bf(c.x); o.y = f2bf(c.y); o.z = f2bf(c.z); o.w = f2bf(c.w);
      *(ushort4*)(C + (size_t)m * N + n) = o;
    } else {
      float* C = (float*)Cv;
      *(float4*)(C + (size_t)m * N + n) = c;
    }
  }
}

// ---------------------------------------------------------------------------
// Kernel 3: MFMA sigmoid attention, causal. Block = 64 q-rows for one (b,h).
// 4 waves; wave w owns q-rows w*16..w*16+15. Streams 64-key tiles.
// qkv is bf16 [B,S,3,H,HD]. ctx written fp32 in [B,S,H*HD] layout.
//
// LDS layouts (stride 72 bf16 = 144 B -> 16B-aligned b128, no pow2 alias):
//   Qs[q][d], Ks[k][d]   row-major (A/B frags = 8 contiguous bf16)
//   Vt[d][key]           transposed, key XOR-block-swizzled vs (d>>3)
//   Ps[q][key]           P round-trip C-layout -> A-layout (per-wave private)
// ---------------------------------------------------------------------------
__global__ __launch_bounds__(256) void attn_mfma(
    const unsigned short* __restrict__ qkv, const float* __restrict__ rpb,
    float* __restrict__ ctxg) {
  __shared__ unsigned short Qs[64][72];
  __shared__ unsigned short Ks[64][72];
  __shared__ unsigned short Vt[64][72];
  __shared__ unsigned short Ps[64][72];

  int qt = gridDim.x - 1 - blockIdx.x;  // heavy (long) blocks first
  int q0 = qt * 64;
  int bh = blockIdx.y;
  int b = bh >> 4, h = bh & 15;
  int t = threadIdx.x;
  int wave = t >> 6, lane = t & 63;
  int quad = lane >> 4, m16 = lane & 15;

  size_t tokbase = (size_t)b * SS * 3072 + (size_t)h * 64;  // bf16 elements

  // load Q tile (rows q0..q0+63)
  {
    int row = t >> 3;            // 0..31
    int cg = (t & 7) * 8;        // 0,8,..,56
    const unsigned short* src = qkv + tokbase + (size_t)(q0 + row) * 3072 + cg;
    *(uint4*)&Qs[row][cg] = *(const uint4*)src;
    *(uint4*)&Qs[row + 32][cg] = *(const uint4*)(src + (size_t)32 * 3072);
  }

  f32x4 zero4 = {0.f, 0.f, 0.f, 0.f};
  f32x4 cacc[4];
#pragma unroll
  for (int nb = 0; nb < 4; ++nb) cacc[nb] = zero4;

  float hb = rpb[h];
  const float scale = 0.125f;  // HD^-0.5
  int ntiles = qt + 1;

  for (int kt = 0; kt < ntiles; ++kt) {
    int k0 = kt * 64;
    __syncthreads();  // prev-iter readers of Ks/Vt done (covers Qs on iter 0)
    {
      int row = t >> 3;
      int cg = (t & 7) * 8;
      const unsigned short* ks = qkv + tokbase + 1024 + (size_t)(k0 + row) * 3072 + cg;
      const unsigned short* vs = qkv + tokbase + 2048 + (size_t)(k0 + row) * 3072 + cg;
      *(uint4*)&Ks[row][cg] = *(const uint4*)ks;
      *(uint4*)&Ks[row + 32][cg] = *(const uint4*)(ks + (size_t)32 * 3072);
      uint4 v0 = *(const uint4*)vs;
      uint4 v1 = *(const uint4*)(vs + (size_t)32 * 3072);
      const unsigned short* e0 = (const unsigned short*)&v0;
      const unsigned short* e1 = (const unsigned short*)&v1;
      // transpose into Vt[d][key], key blocks XOR-swizzled by (d>>3)&7
#pragma unroll
      for (int j = 0; j < 8; ++j) {
        int d = cg + j;
        int sw = (d >> 3) & 7;
        int key0 = row;        // block row>>3, offset row&7
        int key1 = row + 32;
        Vt[d][(((key0 >> 3) ^ sw) << 3) + (key0 & 7)] = e0[j];
        Vt[d][(((key1 >> 3) ^ sw) << 3) + (key1 & 7)] = e1[j];
      }
    }
    __syncthreads();

    // S = Q K^T (16x64 per wave)
    f32x4 sacc[4];
#pragma unroll
    for (int nb = 0; nb < 4; ++nb) sacc[nb] = zero4;
#pragma unroll
    for (int s = 0; s < 2; ++s) {
      short8 a = *(const short8*)&Qs[wave * 16 + m16][s * 32 + quad * 8];
#pragma unroll
      for (int nb = 0; nb < 4; ++nb) {
        short8 bf = *(const short8*)&Ks[nb * 16 + m16][s * 32 + quad * 8];
        sacc[nb] = __builtin_amdgcn_mfma_f32_16x16x32_bf16(a, bf, sacc[nb], 0, 0, 0);
      }
    }

    // sigmoid + causal mask; C-layout -> Ps[q][key] bf16 (own rows only)
#pragma unroll
    for (int nb = 0; nb < 4; ++nb) {
      int key = k0 + nb * 16 + m16;
#pragma unroll
      for (int r = 0; r < 4; ++r) {
        int q = q0 + wave * 16 + quad * 4 + r;
        float sv = sacc[nb][r] * scale + hb;
        float p = (key <= q) ? 1.0f / (1.0f + __expf(-sv)) : 0.f;
        Ps[wave * 16 + quad * 4 + r][nb * 16 + m16] = f2bf(p);
      }
    }
    // no barrier: wave reads only its own Ps rows; LDS ops in-wave are ordered

    // ctx += P V  (16x64 per wave)
#pragma unroll
    for (int s = 0; s < 2; ++s) {
      short8 a = *(const short8*)&Ps[wave * 16 + m16][s * 32 + quad * 8];
#pragma unroll
      for (int nb = 0; nb < 4; ++nb) {
        int d0 = nb * 16 + m16;
        int kb = ((s * 4 + quad) ^ (d0 >> 3)) << 3;  // un-swizzle key block
        short8 bf = *(const short8*)&Vt[d0][kb];
        cacc[nb] = __builtin_amdgcn_mfma_f32_16x16x32_bf16(a, bf, cacc[nb], 0, 0, 0);
      }
    }
  }

  // store ctx fp32 at [b, q, h*64 + d]
#pragma unroll
  for (int nb = 0; nb < 4; ++nb) {
#pragma unroll
    for (int r = 0; r < 4; ++r) {
      int q = q0 + wave * 16 + quad * 4 + r;
      int d = h * 64 + nb * 16 + m16;
      ctxg[(size_t)(b * SS + q) * DD + d] = cacc[nb][r];
    }
  }
}

// ---------------------------------------------------------------------------
extern "C" void kernel_launch(void* const* d_in, const int* in_sizes, int n_in,
                              void* d_out, int out_size, void* d_ws, size_t ws_size,
                              hipStream_t stream) {
  const float* x      = (const float*)d_in[0];
  // d_in[1] = attention_mask (causal tril) — computed analytically, not read
  const float* gamma  = (const float*)d_in[2];
  const float* beta   = (const float*)d_in[3];
  const float* w_qkv  = (const float*)d_in[4];
  const float* b_qkv  = (const float*)d_in[5];
  const float* w_gate = (const float*)d_in[6];
  const float* b_gate = (const float*)d_in[7];
  const float* w_out  = (const float*)d_in[8];
  const float* b_out  = (const float*)d_in[9];
  const float* rpb    = (const float*)d_in[10];
  float* out = (float*)d_out;

  float* xn            = (float*)d_ws;                   // 4096*1024 f32
  unsigned short* qkvb = (unsigned short*)(xn + 4194304); // 4096*3072 bf16
  float* u             = (float*)(qkvb + 12582912);       // 4096*1024 f32
  float* ctx           = u + 4194304;                     // 4096*1024 f32

  // 1. LayerNorm
  ln_kernel<<<BB * SS, 256, 0, stream>>>(x, gamma, beta, xn);
  // 2. QKV projection -> bf16: [4096,1024] @ [1024,3072]
  gemm_fused<0, false, false, true><<<dim3(3072 / 64, 4096 / 64), 256, 0, stream>>>(
      xn, nullptr, w_qkv, b_qkv, nullptr, qkvb, 3072);
  // 3. Gate projection + SiLU: [4096,1024] @ [1024,1024]
  gemm_fused<1, false, false, false><<<dim3(1024 / 64, 4096 / 64), 256, 0, stream>>>(
      xn, nullptr, w_gate, b_gate, nullptr, u, 1024);
  // 4. MFMA sigmoid attention (causal), ctx in [B,S,D] layout
  attn_mfma<<<dim3(SS / 64, BB * HH), 256, 0, stream>>>(qkvb, rpb, ctx);
  // 5. Output projection: (ctx * u) @ w_out + b_out + x
  gemm_fused<0, true, true, false><<<dim3(1024 / 64, 4096 / 64), 256, 0, stream>>>(
      ctx, u, w_out, b_out, x, out, 1024);
}

// Round 5
// 339.610 us; speedup vs baseline: 13.1551x; 2.3965x over previous
//
#include <hip/hip_runtime.h>
#include <hip/hip_bf16.h>
#include <cmath>

// Problem constants (HSTU layer): B=2, S=2048, D=1024, H=16, HD=64
#define BB 2
#define SS 2048
#define DD 1024
#define HH 16
#define EPS 1e-5f

typedef __attribute__((ext_vector_type(8))) short short8;   // 8 bf16 (4 VGPRs)
typedef __attribute__((ext_vector_type(4))) float f32x4;    // 4 fp32 acc

__device__ inline unsigned short f2bf(float f) {
  union { float f; unsigned int u; } v; v.f = f;
  unsigned int u = v.u;
  unsigned int r = (u + 0x7FFFu + ((u >> 16) & 1u)) >> 16;  // RNE
  return (unsigned short)r;
}
__device__ inline float bf2f(unsigned short h) {
  union { unsigned int u; float f; } v; v.u = ((unsigned int)h) << 16;
  return v.f;
}

// ---------------------------------------------------------------------------
// Kernel 1: LayerNorm over D=1024, bf16 output. One block (256 thr) per row.
// ---------------------------------------------------------------------------
__global__ __launch_bounds__(256) void ln_kernel(
    const float* __restrict__ x, const float* __restrict__ gamma,
    const float* __restrict__ beta, unsigned short* __restrict__ xn) {
  int row = blockIdx.x;
  int t = threadIdx.x;
  const float* xr = x + (size_t)row * DD;
  float4 v = *(const float4*)(xr + t * 4);
  float s = v.x + v.y + v.z + v.w;
  float sq = v.x * v.x + v.y * v.y + v.z * v.z + v.w * v.w;
  for (int off = 32; off > 0; off >>= 1) {
    s += __shfl_down(s, off, 64);
    sq += __shfl_down(sq, off, 64);
  }
  __shared__ float ls[4], lq[4];
  int wave = t >> 6, lane = t & 63;
  if (lane == 0) { ls[wave] = s; lq[wave] = sq; }
  __syncthreads();
  float tot = ls[0] + ls[1] + ls[2] + ls[3];
  float totq = lq[0] + lq[1] + lq[2] + lq[3];
  float mu = tot * (1.0f / DD);
  float var = totq * (1.0f / DD) - mu * mu;
  float rstd = rsqrtf(var + EPS);
  float4 g = *(const float4*)(gamma + t * 4);
  float4 bt = *(const float4*)(beta + t * 4);
  ushort4 o;
  o.x = f2bf((v.x - mu) * rstd * g.x + bt.x);
  o.y = f2bf((v.y - mu) * rstd * g.y + bt.y);
  o.z = f2bf((v.z - mu) * rstd * g.z + bt.z);
  o.w = f2bf((v.w - mu) * rstd * g.w + bt.w);
  *(ushort4*)(xn + (size_t)row * DD + t * 4) = o;
}

// ---------------------------------------------------------------------------
// Kernel 2: transpose+cast weights: fp32 W[K][N] -> bf16 Wt[N][K]
// 256 threads = 32x8; 32x32 tiles.
// ---------------------------------------------------------------------------
__global__ __launch_bounds__(256) void wtrans(
    const float* __restrict__ W, unsigned short* __restrict__ Wt,
    int K, int N) {
  __shared__ unsigned short tile[32][33];
  int bx = blockIdx.x * 32;  // col base (N dim)
  int by = blockIdx.y * 32;  // row base (K dim)
  int tx = threadIdx.x & 31, ty = threadIdx.x >> 5;
#pragma unroll
  for (int i = 0; i < 32; i += 8)
    tile[ty + i][tx] = f2bf(W[(size_t)(by + ty + i) * N + bx + tx]);
  __syncthreads();
#pragma unroll
  for (int i = 0; i < 32; i += 8)
    Wt[(size_t)(bx + ty + i) * K + by + tx] = tile[tx][ty + i];
}

// ---------------------------------------------------------------------------
// Kernel 3: bf16 MFMA GEMM. C[M,N] = A[M,K] @ Bt[N,K]^T.
// 128x128 tile, BK=32, 256 threads / 4 waves, each wave 64x64 (4x4 frags).
// Staging: explicit uint4 global loads -> ds_write_b128 (no global_load_lds;
// the async builtin is the prime suspect for the round-3/4 container hangs).
// EPI: 0 = +bias -> bf16 ; 1 = +bias,SiLU -> bf16 ; 2 = +bias,+resid -> f32
// K=1024 fixed.
// ---------------------------------------------------------------------------
template <int EPI>
__global__ __launch_bounds__(256) void gemm_mfma(
    const unsigned short* __restrict__ A, const unsigned short* __restrict__ Bt,
    const float* __restrict__ bias, const float* __restrict__ resid,
    void* __restrict__ Cv, int N) {
  __shared__ unsigned short As[128 * 32];  // [m][k], stride 32
  __shared__ unsigned short Bs[128 * 32];  // [n][k]
  const int K = 1024;
  int tid = threadIdx.x;
  int wave = tid >> 6, lane = tid & 63;
  int quad = lane >> 4, m16 = lane & 15;
  int wm = wave >> 1, wn = wave & 1;
  int m0 = blockIdx.y * 128, n0 = blockIdx.x * 128;

  int lrow = tid >> 2;         // 0..63 (rows lrow and lrow+64)
  int lcol = (tid & 3) * 8;    // bf16 col offset: 0,8,16,24

  f32x4 acc[4][4];
#pragma unroll
  for (int i = 0; i < 4; ++i)
#pragma unroll
    for (int j = 0; j < 4; ++j) acc[i][j] = (f32x4){0.f, 0.f, 0.f, 0.f};

  for (int k0 = 0; k0 < K; k0 += 32) {
    uint4 a0 = *(const uint4*)(A + (size_t)(m0 + lrow) * K + k0 + lcol);
    uint4 a1 = *(const uint4*)(A + (size_t)(m0 + lrow + 64) * K + k0 + lcol);
    uint4 b0 = *(const uint4*)(Bt + (size_t)(n0 + lrow) * K + k0 + lcol);
    uint4 b1 = *(const uint4*)(Bt + (size_t)(n0 + lrow + 64) * K + k0 + lcol);
    __syncthreads();  // prev-iter readers done before overwrite
    *(uint4*)&As[lrow * 32 + lcol] = a0;
    *(uint4*)&As[(lrow + 64) * 32 + lcol] = a1;
    *(uint4*)&Bs[lrow * 32 + lcol] = b0;
    *(uint4*)&Bs[(lrow + 64) * 32 + lcol] = b1;
    __syncthreads();
    short8 af[4], bfr[4];
#pragma unroll
    for (int mi = 0; mi < 4; ++mi)
      af[mi] = *(const short8*)&As[(wm * 64 + mi * 16 + m16) * 32 + quad * 8];
#pragma unroll
    for (int ni = 0; ni < 4; ++ni)
      bfr[ni] = *(const short8*)&Bs[(wn * 64 + ni * 16 + m16) * 32 + quad * 8];
#pragma unroll
    for (int mi = 0; mi < 4; ++mi)
#pragma unroll
      for (int ni = 0; ni < 4; ++ni)
        acc[mi][ni] = __builtin_amdgcn_mfma_f32_16x16x32_bf16(
            af[mi], bfr[ni], acc[mi][ni], 0, 0, 0);
  }

  // epilogue: C-layout col = m16, row = quad*4 + r
#pragma unroll
  for (int ni = 0; ni < 4; ++ni) {
    int col = n0 + wn * 64 + ni * 16 + m16;
    float bb = bias[col];
#pragma unroll
    for (int mi = 0; mi < 4; ++mi) {
#pragma unroll
      for (int r = 0; r < 4; ++r) {
        int row = m0 + wm * 64 + mi * 16 + quad * 4 + r;
        float v = acc[mi][ni][r] + bb;
        if (EPI == 1) v = v / (1.0f + __expf(-v));
        if (EPI == 2) {
          v += resid[(size_t)row * N + col];
          ((float*)Cv)[(size_t)row * N + col] = v;
        } else {
          ((unsigned short*)Cv)[(size_t)row * N + col] = f2bf(v);
        }
      }
    }
  }
}

// ---------------------------------------------------------------------------
// Kernel 4: MFMA sigmoid attention, causal. Block = 64 q-rows for one (b,h).
// qkv bf16 [B,S,3,H,HD]; ctx bf16 out in [B,S,H*HD] layout.
// ---------------------------------------------------------------------------
__global__ __launch_bounds__(256) void attn_mfma(
    const unsigned short* __restrict__ qkv, const float* __restrict__ rpb,
    unsigned short* __restrict__ ctxg) {
  __shared__ unsigned short Qs[64][72];
  __shared__ unsigned short Ks[64][72];
  __shared__ unsigned short Vt[64][72];
  __shared__ unsigned short Ps[64][72];

  int qt = gridDim.x - 1 - blockIdx.x;  // heavy (long) blocks first
  int q0 = qt * 64;
  int bh = blockIdx.y;
  int b = bh >> 4, h = bh & 15;
  int t = threadIdx.x;
  int wave = t >> 6, lane = t & 63;
  int quad = lane >> 4, m16 = lane & 15;

  size_t tokbase = (size_t)b * SS * 3072 + (size_t)h * 64;

  {
    int row = t >> 3;
    int cg = (t & 7) * 8;
    const unsigned short* src = qkv + tokbase + (size_t)(q0 + row) * 3072 + cg;
    *(uint4*)&Qs[row][cg] = *(const uint4*)src;
    *(uint4*)&Qs[row + 32][cg] = *(const uint4*)(src + (size_t)32 * 3072);
  }

  f32x4 zero4 = {0.f, 0.f, 0.f, 0.f};
  f32x4 cacc[4];
#pragma unroll
  for (int nb = 0; nb < 4; ++nb) cacc[nb] = zero4;

  float hb = rpb[h];
  const float scale = 0.125f;
  int ntiles = qt + 1;

  for (int kt = 0; kt < ntiles; ++kt) {
    int k0 = kt * 64;
    __syncthreads();
    {
      int row = t >> 3;
      int cg = (t & 7) * 8;
      const unsigned short* ks = qkv + tokbase + 1024 + (size_t)(k0 + row) * 3072 + cg;
      const unsigned short* vs = qkv + tokbase + 2048 + (size_t)(k0 + row) * 3072 + cg;
      *(uint4*)&Ks[row][cg] = *(const uint4*)ks;
      *(uint4*)&Ks[row + 32][cg] = *(const uint4*)(ks + (size_t)32 * 3072);
      uint4 v0 = *(const uint4*)vs;
      uint4 v1 = *(const uint4*)(vs + (size_t)32 * 3072);
      const unsigned short* e0 = (const unsigned short*)&v0;
      const unsigned short* e1 = (const unsigned short*)&v1;
#pragma unroll
      for (int j = 0; j < 8; ++j) {
        int d = cg + j;
        int sw = (d >> 3) & 7;
        int key0 = row, key1 = row + 32;
        Vt[d][(((key0 >> 3) ^ sw) << 3) + (key0 & 7)] = e0[j];
        Vt[d][(((key1 >> 3) ^ sw) << 3) + (key1 & 7)] = e1[j];
      }
    }
    __syncthreads();

    f32x4 sacc[4];
#pragma unroll
    for (int nb = 0; nb < 4; ++nb) sacc[nb] = zero4;
#pragma unroll
    for (int s = 0; s < 2; ++s) {
      short8 a = *(const short8*)&Qs[wave * 16 + m16][s * 32 + quad * 8];
#pragma unroll
      for (int nb = 0; nb < 4; ++nb) {
        short8 bf = *(const short8*)&Ks[nb * 16 + m16][s * 32 + quad * 8];
        sacc[nb] = __builtin_amdgcn_mfma_f32_16x16x32_bf16(a, bf, sacc[nb], 0, 0, 0);
      }
    }

#pragma unroll
    for (int nb = 0; nb < 4; ++nb) {
      int key = k0 + nb * 16 + m16;
#pragma unroll
      for (int r = 0; r < 4; ++r) {
        int q = q0 + wave * 16 + quad * 4 + r;
        float sv = sacc[nb][r] * scale + hb;
        float p = (key <= q) ? 1.0f / (1.0f + __expf(-sv)) : 0.f;
        Ps[wave * 16 + quad * 4 + r][nb * 16 + m16] = f2bf(p);
      }
    }

#pragma unroll
    for (int s = 0; s < 2; ++s) {
      short8 a = *(const short8*)&Ps[wave * 16 + m16][s * 32 + quad * 8];
#pragma unroll
      for (int nb = 0; nb < 4; ++nb) {
        int d0 = nb * 16 + m16;
        int kb = ((s * 4 + quad) ^ (d0 >> 3)) << 3;
        short8 bf = *(const short8*)&Vt[d0][kb];
        cacc[nb] = __builtin_amdgcn_mfma_f32_16x16x32_bf16(a, bf, cacc[nb], 0, 0, 0);
      }
    }
  }

#pragma unroll
  for (int nb = 0; nb < 4; ++nb) {
#pragma unroll
    for (int r = 0; r < 4; ++r) {
      int q = q0 + wave * 16 + quad * 4 + r;
      int d = h * 64 + nb * 16 + m16;
      ctxg[(size_t)(b * SS + q) * DD + d] = f2bf(cacc[nb][r]);
    }
  }
}

// ---------------------------------------------------------------------------
// Kernel 5: prod = bf16(ctx * u), both bf16 in. 8 elems/thread.
// ---------------------------------------------------------------------------
__global__ __launch_bounds__(256) void mulcast(
    const unsigned short* __restrict__ a, const unsigned short* __restrict__ b,
    unsigned short* __restrict__ o) {
  size_t i = ((size_t)blockIdx.x * 256 + threadIdx.x) * 8;
  uint4 av = *(const uint4*)(a + i);
  uint4 bv = *(const uint4*)(b + i);
  const unsigned short* ae = (const unsigned short*)&av;
  const unsigned short* be = (const unsigned short*)&bv;
  ushort4 o0, o1;
  unsigned short* oe0 = (unsigned short*)&o0;
  unsigned short* oe1 = (unsigned short*)&o1;
#pragma unroll
  for (int j = 0; j < 4; ++j) oe0[j] = f2bf(bf2f(ae[j]) * bf2f(be[j]));
#pragma unroll
  for (int j = 0; j < 4; ++j) oe1[j] = f2bf(bf2f(ae[4 + j]) * bf2f(be[4 + j]));
  *(ushort4*)(o + i) = o0;
  *(ushort4*)(o + i + 4) = o1;
}

// ---------------------------------------------------------------------------
extern "C" void kernel_launch(void* const* d_in, const int* in_sizes, int n_in,
                              void* d_out, int out_size, void* d_ws, size_t ws_size,
                              hipStream_t stream) {
  const float* x      = (const float*)d_in[0];
  // d_in[1] = attention_mask (causal tril) — computed analytically, not read
  const float* gamma  = (const float*)d_in[2];
  const float* beta   = (const float*)d_in[3];
  const float* w_qkv  = (const float*)d_in[4];
  const float* b_qkv  = (const float*)d_in[5];
  const float* w_gate = (const float*)d_in[6];
  const float* b_gate = (const float*)d_in[7];
  const float* w_out  = (const float*)d_in[8];
  const float* b_out  = (const float*)d_in[9];
  const float* rpb    = (const float*)d_in[10];
  float* out = (float*)d_out;

  unsigned short* xnb   = (unsigned short*)d_ws;      // 4096*1024
  unsigned short* qkvb  = xnb + 4194304;              // 4096*3072
  unsigned short* ub    = qkvb + 12582912;            // 4096*1024
  unsigned short* ctxb  = ub + 4194304;               // 4096*1024
  unsigned short* prodb = ctxb + 4194304;             // 4096*1024
  unsigned short* wqkvT = prodb + 4194304;            // 3072*1024
  unsigned short* wgateT = wqkvT + 3145728;           // 1024*1024
  unsigned short* woutT  = wgateT + 1048576;          // 1024*1024
  // total ~66 MB

  // 1. LayerNorm -> bf16
  ln_kernel<<<BB * SS, 256, 0, stream>>>(x, gamma, beta, xnb);
  // 2. Weight transposes fp32[K][N] -> bf16[N][K]
  wtrans<<<dim3(3072 / 32, 1024 / 32), 256, 0, stream>>>(w_qkv, wqkvT, 1024, 3072);
  wtrans<<<dim3(1024 / 32, 1024 / 32), 256, 0, stream>>>(w_gate, wgateT, 1024, 1024);
  wtrans<<<dim3(1024 / 32, 1024 / 32), 256, 0, stream>>>(w_out, woutT, 1024, 1024);
  // 3. QKV projection -> bf16: [4096,1024] @ [1024,3072]
  gemm_mfma<0><<<dim3(3072 / 128, 4096 / 128), 256, 0, stream>>>(
      xnb, wqkvT, b_qkv, nullptr, qkvb, 3072);
  // 4. Gate projection + SiLU -> bf16
  gemm_mfma<1><<<dim3(1024 / 128, 4096 / 128), 256, 0, stream>>>(
      xnb, wgateT, b_gate, nullptr, ub, 1024);
  // 5. MFMA sigmoid attention (causal), ctx bf16 in [B,S,D] layout
  attn_mfma<<<dim3(SS / 64, BB * HH), 256, 0, stream>>>(qkvb, rpb, ctxb);
  // 6. prod = bf16(ctx * u)
  mulcast<<<4194304 / (256 * 8), 256, 0, stream>>>(ctxb, ub, prodb);
  // 7. Output projection: prod @ w_out + b_out + x -> f32 out
  gemm_mfma<2><<<dim3(1024 / 128, 4096 / 128), 256, 0, stream>>>(
      prodb, woutT, b_out, x, out, 1024);
}

// Round 6
// 281.046 us; speedup vs baseline: 15.8963x; 1.2084x over previous
//
#include <hip/hip_runtime.h>
#include <hip/hip_bf16.h>
#include <cmath>

// Problem constants (HSTU layer): B=2, S=2048, D=1024, H=16, HD=64
#define BB 2
#define SS 2048
#define DD 1024
#define HH 16
#define EPS 1e-5f
#define LOG2E 1.44269504088896f
#define QSCALE (0.125f * LOG2E)   // HD^-0.5 * log2(e), folded into q

typedef __attribute__((ext_vector_type(8))) short short8;   // 8 bf16 (4 VGPRs)
typedef __attribute__((ext_vector_type(4))) float f32x4;    // 4 fp32 acc

__device__ inline unsigned short f2bf(float f) {
  union { float f; unsigned int u; } v; v.f = f;
  unsigned int u = v.u;
  unsigned int r = (u + 0x7FFFu + ((u >> 16) & 1u)) >> 16;  // RNE
  return (unsigned short)r;
}
__device__ inline float bf2f(unsigned short h) {
  union { unsigned int u; float f; } v; v.u = ((unsigned int)h) << 16;
  return v.f;
}
// fast pack: round-half-up (differs from RNE only at exact ties)
__device__ inline unsigned short f2bf_fast(float f) {
  union { float f; unsigned int u; } v; v.f = f;
  return (unsigned short)((v.u + 0x8000u) >> 16);
}

// ---------------------------------------------------------------------------
// Kernel 1: LayerNorm over D=1024, bf16 output. One block (256 thr) per row.
// ---------------------------------------------------------------------------
__global__ __launch_bounds__(256) void ln_kernel(
    const float* __restrict__ x, const float* __restrict__ gamma,
    const float* __restrict__ beta, unsigned short* __restrict__ xn) {
  int row = blockIdx.x;
  int t = threadIdx.x;
  const float* xr = x + (size_t)row * DD;
  float4 v = *(const float4*)(xr + t * 4);
  float s = v.x + v.y + v.z + v.w;
  float sq = v.x * v.x + v.y * v.y + v.z * v.z + v.w * v.w;
  for (int off = 32; off > 0; off >>= 1) {
    s += __shfl_down(s, off, 64);
    sq += __shfl_down(sq, off, 64);
  }
  __shared__ float ls[4], lq[4];
  int wave = t >> 6, lane = t & 63;
  if (lane == 0) { ls[wave] = s; lq[wave] = sq; }
  __syncthreads();
  float tot = ls[0] + ls[1] + ls[2] + ls[3];
  float totq = lq[0] + lq[1] + lq[2] + lq[3];
  float mu = tot * (1.0f / DD);
  float var = totq * (1.0f / DD) - mu * mu;
  float rstd = rsqrtf(var + EPS);
  float4 g = *(const float4*)(gamma + t * 4);
  float4 bt = *(const float4*)(beta + t * 4);
  ushort4 o;
  o.x = f2bf((v.x - mu) * rstd * g.x + bt.x);
  o.y = f2bf((v.y - mu) * rstd * g.y + bt.y);
  o.z = f2bf((v.z - mu) * rstd * g.z + bt.z);
  o.w = f2bf((v.w - mu) * rstd * g.w + bt.w);
  *(ushort4*)(xn + (size_t)row * DD + t * 4) = o;
}

// ---------------------------------------------------------------------------
// Kernel 2: transpose+cast weights: fp32 W[K][N] -> bf16 Wt[N][K]
// ---------------------------------------------------------------------------
__global__ __launch_bounds__(256) void wtrans(
    const float* __restrict__ W, unsigned short* __restrict__ Wt,
    int K, int N) {
  __shared__ unsigned short tile[32][33];
  int bx = blockIdx.x * 32;
  int by = blockIdx.y * 32;
  int tx = threadIdx.x & 31, ty = threadIdx.x >> 5;
#pragma unroll
  for (int i = 0; i < 32; i += 8)
    tile[ty + i][tx] = f2bf(W[(size_t)(by + ty + i) * N + bx + tx]);
  __syncthreads();
#pragma unroll
  for (int i = 0; i < 32; i += 8)
    Wt[(size_t)(bx + ty + i) * K + by + tx] = tile[tx][ty + i];
}

// ---------------------------------------------------------------------------
// Kernel 3: fused QKV+gate bf16 MFMA GEMM. A[4096,1024] @ Wcat[4096,1024]^T.
// 128x128 tile, BK=32, 4 waves. N=4096 sections (wave-uniform per 64-col win):
//   [0,1024)  q  -> qkb[token][col], scaled by QSCALE (after bias)
//   [1024,2048) k -> qkb[token][col]
//   [2048,3072) v -> vT[(b*16+h)*64+d][s]  (transposed for attention)
//   [3072,4096) gate -> SiLU -> ub[token][col-3072]
// ---------------------------------------------------------------------------
__global__ __launch_bounds__(256) void gemm_qkvg(
    const unsigned short* __restrict__ A, const unsigned short* __restrict__ Bt,
    const float* __restrict__ bqkv, const float* __restrict__ bgate,
    unsigned short* __restrict__ qkb, unsigned short* __restrict__ vTb,
    unsigned short* __restrict__ ub) {
  __shared__ unsigned short As[128 * 32];
  __shared__ unsigned short Bs[128 * 32];
  const int K = 1024;
  int tid = threadIdx.x;
  int wave = tid >> 6, lane = tid & 63;
  int quad = lane >> 4, m16 = lane & 15;
  int wm = wave >> 1, wn = wave & 1;
  int m0 = blockIdx.y * 128, n0 = blockIdx.x * 128;

  int lrow = tid >> 2;
  int lcol = (tid & 3) * 8;

  f32x4 acc[4][4];
#pragma unroll
  for (int i = 0; i < 4; ++i)
#pragma unroll
    for (int j = 0; j < 4; ++j) acc[i][j] = (f32x4){0.f, 0.f, 0.f, 0.f};

  for (int k0 = 0; k0 < K; k0 += 32) {
    uint4 a0 = *(const uint4*)(A + (size_t)(m0 + lrow) * K + k0 + lcol);
    uint4 a1 = *(const uint4*)(A + (size_t)(m0 + lrow + 64) * K + k0 + lcol);
    uint4 b0 = *(const uint4*)(Bt + (size_t)(n0 + lrow) * K + k0 + lcol);
    uint4 b1 = *(const uint4*)(Bt + (size_t)(n0 + lrow + 64) * K + k0 + lcol);
    __syncthreads();
    *(uint4*)&As[lrow * 32 + lcol] = a0;
    *(uint4*)&As[(lrow + 64) * 32 + lcol] = a1;
    *(uint4*)&Bs[lrow * 32 + lcol] = b0;
    *(uint4*)&Bs[(lrow + 64) * 32 + lcol] = b1;
    __syncthreads();
    short8 af[4], bfr[4];
#pragma unroll
    for (int mi = 0; mi < 4; ++mi)
      af[mi] = *(const short8*)&As[(wm * 64 + mi * 16 + m16) * 32 + quad * 8];
#pragma unroll
    for (int ni = 0; ni < 4; ++ni)
      bfr[ni] = *(const short8*)&Bs[(wn * 64 + ni * 16 + m16) * 32 + quad * 8];
#pragma unroll
    for (int mi = 0; mi < 4; ++mi)
#pragma unroll
      for (int ni = 0; ni < 4; ++ni)
        acc[mi][ni] = __builtin_amdgcn_mfma_f32_16x16x32_bf16(
            af[mi], bfr[ni], acc[mi][ni], 0, 0, 0);
  }

  int nwin = n0 + wn * 64;      // 64-col window base (wave-uniform)
  int sec = nwin >> 10;         // 0=q 1=k 2=v 3=gate
  if (sec <= 1) {
    float qs = (sec == 0) ? QSCALE : 1.0f;
#pragma unroll
    for (int ni = 0; ni < 4; ++ni) {
      int col = nwin + ni * 16 + m16;
      float bb = bqkv[col];
#pragma unroll
      for (int mi = 0; mi < 4; ++mi)
#pragma unroll
        for (int r = 0; r < 4; ++r) {
          int row = m0 + wm * 64 + mi * 16 + quad * 4 + r;
          qkb[(size_t)row * 2048 + col] = f2bf((acc[mi][ni][r] + bb) * qs);
        }
    }
  } else if (sec == 2) {
#pragma unroll
    for (int ni = 0; ni < 4; ++ni) {
      int col = nwin + ni * 16 + m16;
      float bb = bqkv[col];
      int vcol = col - 2048;
      int hh = vcol >> 6, dd = vcol & 63;
#pragma unroll
      for (int mi = 0; mi < 4; ++mi) {
        int row0 = m0 + wm * 64 + mi * 16 + quad * 4;
        int bat = row0 >> 11, s0 = row0 & 2047;
        ushort4 o;
        o.x = f2bf(acc[mi][ni][0] + bb);
        o.y = f2bf(acc[mi][ni][1] + bb);
        o.z = f2bf(acc[mi][ni][2] + bb);
        o.w = f2bf(acc[mi][ni][3] + bb);
        *(ushort4*)&vTb[(size_t)((bat * 16 + hh) * 64 + dd) * 2048 + s0] = o;
      }
    }
  } else {
#pragma unroll
    for (int ni = 0; ni < 4; ++ni) {
      int col = nwin + ni * 16 + m16;
      int g = col - 3072;
      float bb = bgate[g];
#pragma unroll
      for (int mi = 0; mi < 4; ++mi)
#pragma unroll
        for (int r = 0; r < 4; ++r) {
          int row = m0 + wm * 64 + mi * 16 + quad * 4 + r;
          float v = acc[mi][ni][r] + bb;
          v = v * __builtin_amdgcn_rcpf(1.0f + exp2f(-v * LOG2E));  // SiLU
          ub[(size_t)row * 1024 + g] = f2bf(v);
        }
    }
  }
}

// ---------------------------------------------------------------------------
// Kernel 4: output GEMM: prod[4096,1024] @ wout[1024,1024]^T + b + x -> f32
// ---------------------------------------------------------------------------
__global__ __launch_bounds__(256) void gemm_out(
    const unsigned short* __restrict__ A, const unsigned short* __restrict__ Bt,
    const float* __restrict__ bias, const float* __restrict__ resid,
    float* __restrict__ C) {
  __shared__ unsigned short As[128 * 32];
  __shared__ unsigned short Bs[128 * 32];
  const int K = 1024, N = 1024;
  int tid = threadIdx.x;
  int wave = tid >> 6, lane = tid & 63;
  int quad = lane >> 4, m16 = lane & 15;
  int wm = wave >> 1, wn = wave & 1;
  int m0 = blockIdx.y * 128, n0 = blockIdx.x * 128;
  int lrow = tid >> 2;
  int lcol = (tid & 3) * 8;

  f32x4 acc[4][4];
#pragma unroll
  for (int i = 0; i < 4; ++i)
#pragma unroll
    for (int j = 0; j < 4; ++j) acc[i][j] = (f32x4){0.f, 0.f, 0.f, 0.f};

  for (int k0 = 0; k0 < K; k0 += 32) {
    uint4 a0 = *(const uint4*)(A + (size_t)(m0 + lrow) * K + k0 + lcol);
    uint4 a1 = *(const uint4*)(A + (size_t)(m0 + lrow + 64) * K + k0 + lcol);
    uint4 b0 = *(const uint4*)(Bt + (size_t)(n0 + lrow) * K + k0 + lcol);
    uint4 b1 = *(const uint4*)(Bt + (size_t)(n0 + lrow + 64) * K + k0 + lcol);
    __syncthreads();
    *(uint4*)&As[lrow * 32 + lcol] = a0;
    *(uint4*)&As[(lrow + 64) * 32 + lcol] = a1;
    *(uint4*)&Bs[lrow * 32 + lcol] = b0;
    *(uint4*)&Bs[(lrow + 64) * 32 + lcol] = b1;
    __syncthreads();
    short8 af[4], bfr[4];
#pragma unroll
    for (int mi = 0; mi < 4; ++mi)
      af[mi] = *(const short8*)&As[(wm * 64 + mi * 16 + m16) * 32 + quad * 8];
#pragma unroll
    for (int ni = 0; ni < 4; ++ni)
      bfr[ni] = *(const short8*)&Bs[(wn * 64 + ni * 16 + m16) * 32 + quad * 8];
#pragma unroll
    for (int mi = 0; mi < 4; ++mi)
#pragma unroll
      for (int ni = 0; ni < 4; ++ni)
        acc[mi][ni] = __builtin_amdgcn_mfma_f32_16x16x32_bf16(
            af[mi], bfr[ni], acc[mi][ni], 0, 0, 0);
  }
#pragma unroll
  for (int ni = 0; ni < 4; ++ni) {
    int col = n0 + wn * 64 + ni * 16 + m16;
    float bb = bias[col];
#pragma unroll
    for (int mi = 0; mi < 4; ++mi)
#pragma unroll
      for (int r = 0; r < 4; ++r) {
        int row = m0 + wm * 64 + mi * 16 + quad * 4 + r;
        C[(size_t)row * N + col] =
            acc[mi][ni][r] + bb + resid[(size_t)row * N + col];
      }
  }
}

// ---------------------------------------------------------------------------
// Kernel 5: MFMA sigmoid attention, causal, fused *u epilogue.
// qk: [B*S][2048] (q pre-scaled by QSCALE | k), vT: [(b*16+h)*64+d][s],
// u: bf16 [B*S][1024], prod out: bf16 [B*S][1024].
// Mask applied only on the diagonal k-tile (wave-uniform branch).
// ---------------------------------------------------------------------------
__global__ __launch_bounds__(256) void attn_mfma(
    const unsigned short* __restrict__ qk, const unsigned short* __restrict__ vT,
    const unsigned short* __restrict__ u, const float* __restrict__ rpb,
    unsigned short* __restrict__ prod) {
  __shared__ unsigned short Qs[64][72];
  __shared__ unsigned short Ks[64][72];
  __shared__ unsigned short Vt[64][72];
  __shared__ unsigned short Ps[64][72];

  int qt = gridDim.x - 1 - blockIdx.x;  // heavy (long) blocks first
  int q0 = qt * 64;
  int bh = blockIdx.y;
  int b = bh >> 4, h = bh & 15;
  int t = threadIdx.x;
  int wave = t >> 6, lane = t & 63;
  int quad = lane >> 4, m16 = lane & 15;

  const unsigned short* qbase = qk + (size_t)(b * SS) * 2048 + h * 64;
  const unsigned short* kbase = qbase + 1024;
  const unsigned short* vbase = vT + (size_t)(bh * 64) * 2048;

  // Q tile: 64 rows x 64 cols, b128 stages
  {
    int row = t >> 3, blk = t & 7;
    const unsigned short* s0 = qbase + (size_t)(q0 + row) * 2048 + blk * 8;
    *(uint4*)&Qs[row][blk * 8] = *(const uint4*)s0;
    *(uint4*)&Qs[row + 32][blk * 8] = *(const uint4*)(s0 + (size_t)32 * 2048);
  }

  f32x4 zero4 = {0.f, 0.f, 0.f, 0.f};
  f32x4 cacc[4];
#pragma unroll
  for (int nb = 0; nb < 4; ++nb) cacc[nb] = zero4;

  float hb2 = rpb[h] * LOG2E;
  int ntiles = qt + 1;

  for (int kt = 0; kt < ntiles; ++kt) {
    int k0 = kt * 64;
    bool diag = (kt == qt);
    int row = t >> 3, blk = t & 7;
    const unsigned short* ks = kbase + (size_t)(k0 + row) * 2048 + blk * 8;
    uint4 k0v = *(const uint4*)ks;
    uint4 k1v = *(const uint4*)(ks + (size_t)32 * 2048);
    const unsigned short* vs = vbase + (size_t)row * 2048 + k0 + blk * 8;
    uint4 v0v = *(const uint4*)vs;
    uint4 v1v = *(const uint4*)(vs + (size_t)32 * 2048);
    __syncthreads();  // prev-iter readers done (covers Qs on iter 0)
    *(uint4*)&Ks[row][blk * 8] = k0v;
    *(uint4*)&Ks[row + 32][blk * 8] = k1v;
    *(uint4*)&Vt[row][blk * 8] = v0v;    // Vt[d][key]
    *(uint4*)&Vt[row + 32][blk * 8] = v1v;
    __syncthreads();

    // S = Q K^T (16 q-rows x 64 keys per wave); q pre-scaled by QSCALE
    f32x4 sacc[4];
#pragma unroll
    for (int nb = 0; nb < 4; ++nb) sacc[nb] = zero4;
#pragma unroll
    for (int s = 0; s < 2; ++s) {
      short8 a = *(const short8*)&Qs[wave * 16 + m16][s * 32 + quad * 8];
#pragma unroll
      for (int nb = 0; nb < 4; ++nb) {
        short8 bf = *(const short8*)&Ks[nb * 16 + m16][s * 32 + quad * 8];
        sacc[nb] = __builtin_amdgcn_mfma_f32_16x16x32_bf16(a, bf, sacc[nb], 0, 0, 0);
      }
    }

    // p = sigmoid(scale*s + hb) = rcp(1 + exp2(-(sacc + hb2)))
#pragma unroll
    for (int nb = 0; nb < 4; ++nb) {
#pragma unroll
      for (int r = 0; r < 4; ++r) {
        float y = sacc[nb][r] + hb2;
        float p = __builtin_amdgcn_rcpf(1.0f + exp2f(-y));
        if (diag) {
          int key = k0 + nb * 16 + m16;
          int q = q0 + wave * 16 + quad * 4 + r;
          if (key > q) p = 0.f;
        }
        Ps[wave * 16 + quad * 4 + r][nb * 16 + m16] = f2bf_fast(p);
      }
    }
    // no barrier: wave reads only its own Ps rows (in-wave LDS ordering)

    // ctx += P V
#pragma unroll
    for (int s = 0; s < 2; ++s) {
      short8 a = *(const short8*)&Ps[wave * 16 + m16][s * 32 + quad * 8];
#pragma unroll
      for (int nb = 0; nb < 4; ++nb) {
        short8 bf = *(const short8*)&Vt[nb * 16 + m16][s * 32 + quad * 8];
        cacc[nb] = __builtin_amdgcn_mfma_f32_16x16x32_bf16(a, bf, cacc[nb], 0, 0, 0);
      }
    }
  }

  // epilogue: prod = bf16(ctx * u), layout [token][h*64+d]
  const unsigned short* ub_ = u + (size_t)(b * SS) * 1024 + h * 64;
  unsigned short* pb_ = prod + (size_t)(b * SS) * 1024 + h * 64;
#pragma unroll
  for (int nb = 0; nb < 4; ++nb) {
    int d = nb * 16 + m16;
#pragma unroll
    for (int r = 0; r < 4; ++r) {
      int q = q0 + wave * 16 + quad * 4 + r;
      float uv = bf2f(ub_[(size_t)q * 1024 + d]);
      pb_[(size_t)q * 1024 + d] = f2bf(cacc[nb][r] * uv);
    }
  }
}

// ---------------------------------------------------------------------------
extern "C" void kernel_launch(void* const* d_in, const int* in_sizes, int n_in,
                              void* d_out, int out_size, void* d_ws, size_t ws_size,
                              hipStream_t stream) {
  const float* x      = (const float*)d_in[0];
  // d_in[1] = attention_mask (causal tril) — computed analytically, not read
  const float* gamma  = (const float*)d_in[2];
  const float* beta   = (const float*)d_in[3];
  const float* w_qkv  = (const float*)d_in[4];
  const float* b_qkv  = (const float*)d_in[5];
  const float* w_gate = (const float*)d_in[6];
  const float* b_gate = (const float*)d_in[7];
  const float* w_out  = (const float*)d_in[8];
  const float* b_out  = (const float*)d_in[9];
  const float* rpb    = (const float*)d_in[10];
  float* out = (float*)d_out;

  unsigned short* xnb   = (unsigned short*)d_ws;  // 4096*1024
  unsigned short* qkb   = xnb + 4194304;          // 4096*2048 (q|k)
  unsigned short* vTb   = qkb + 8388608;          // 32*64*2048
  unsigned short* ub    = vTb + 4194304;          // 4096*1024
  unsigned short* prodb = ub + 4194304;           // 4096*1024
  unsigned short* wcatT = prodb + 4194304;        // 4096*1024 (qkv|gate rows)
  unsigned short* woutT = wcatT + 4194304;        // 1024*1024
  // total ~60 MB

  // 1. LayerNorm -> bf16
  ln_kernel<<<BB * SS, 256, 0, stream>>>(x, gamma, beta, xnb);
  // 2. Weight transposes fp32[K][N] -> bf16[N][K]; gate rows appended at 3072
  wtrans<<<dim3(3072 / 32, 1024 / 32), 256, 0, stream>>>(w_qkv, wcatT, 1024, 3072);
  wtrans<<<dim3(1024 / 32, 1024 / 32), 256, 0, stream>>>(w_gate, wcatT + (size_t)3072 * 1024, 1024, 1024);
  wtrans<<<dim3(1024 / 32, 1024 / 32), 256, 0, stream>>>(w_out, woutT, 1024, 1024);
  // 3. Fused QKV+gate GEMM: N=4096 sections -> qkb, vTb, ub
  gemm_qkvg<<<dim3(4096 / 128, 4096 / 128), 256, 0, stream>>>(
      xnb, wcatT, b_qkv, b_gate, qkb, vTb, ub);
  // 4. MFMA sigmoid attention + fused *u -> prodb
  attn_mfma<<<dim3(SS / 64, BB * HH), 256, 0, stream>>>(qkb, vTb, ub, rpb, prodb);
  // 5. Output projection: prod @ w_out + b_out + x -> f32 out
  gemm_out<<<dim3(1024 / 128, 4096 / 128), 256, 0, stream>>>(
      prodb, woutT, b_out, x, out);
}

// Round 8
// 254.181 us; speedup vs baseline: 17.5764x; 1.1057x over previous
//
#include <hip/hip_runtime.h>
#include <hip/hip_bf16.h>
#include <cmath>

// Problem constants (HSTU layer): B=2, S=2048, D=1024, H=16, HD=64
#define BB 2
#define SS 2048
#define DD 1024
#define HH 16
#define EPS 1e-5f
#define LOG2E 1.44269504088896f
#define QSCALE (0.125f * LOG2E)   // HD^-0.5 * log2(e), folded into q

typedef __attribute__((ext_vector_type(8))) short short8;   // 8 bf16 (4 VGPRs)
typedef __attribute__((ext_vector_type(4))) float f32x4;    // 4 fp32 acc

__device__ inline unsigned short f2bf(float f) {
  union { float f; unsigned int u; } v; v.f = f;
  unsigned int u = v.u;
  unsigned int r = (u + 0x7FFFu + ((u >> 16) & 1u)) >> 16;  // RNE
  return (unsigned short)r;
}
__device__ inline float bf2f(unsigned short h) {
  union { unsigned int u; float f; } v; v.u = ((unsigned int)h) << 16;
  return v.f;
}
// fast pack: round-half-up (differs from RNE only at exact ties)
__device__ inline unsigned short f2bf_fast(float f) {
  union { float f; unsigned int u; } v; v.f = f;
  return (unsigned short)((v.u + 0x8000u) >> 16);
}

// ---------------------------------------------------------------------------
// Kernel 1: LayerNorm over D=1024, bf16 output. One block (256 thr) per row.
// ---------------------------------------------------------------------------
__global__ __launch_bounds__(256) void ln_kernel(
    const float* __restrict__ x, const float* __restrict__ gamma,
    const float* __restrict__ beta, unsigned short* __restrict__ xn) {
  int row = blockIdx.x;
  int t = threadIdx.x;
  const float* xr = x + (size_t)row * DD;
  float4 v = *(const float4*)(xr + t * 4);
  float s = v.x + v.y + v.z + v.w;
  float sq = v.x * v.x + v.y * v.y + v.z * v.z + v.w * v.w;
  for (int off = 32; off > 0; off >>= 1) {
    s += __shfl_down(s, off, 64);
    sq += __shfl_down(sq, off, 64);
  }
  __shared__ float ls[4], lq[4];
  int wave = t >> 6, lane = t & 63;
  if (lane == 0) { ls[wave] = s; lq[wave] = sq; }
  __syncthreads();
  float tot = ls[0] + ls[1] + ls[2] + ls[3];
  float totq = lq[0] + lq[1] + lq[2] + lq[3];
  float mu = tot * (1.0f / DD);
  float var = totq * (1.0f / DD) - mu * mu;
  float rstd = rsqrtf(var + EPS);
  float4 g = *(const float4*)(gamma + t * 4);
  float4 bt = *(const float4*)(beta + t * 4);
  ushort4 o;
  o.x = f2bf((v.x - mu) * rstd * g.x + bt.x);
  o.y = f2bf((v.y - mu) * rstd * g.y + bt.y);
  o.z = f2bf((v.z - mu) * rstd * g.z + bt.z);
  o.w = f2bf((v.w - mu) * rstd * g.w + bt.w);
  *(ushort4*)(xn + (size_t)row * DD + t * 4) = o;
}

// ---------------------------------------------------------------------------
// Kernel 2: transpose+cast weights: fp32 W[K][N] -> bf16 Wt[N][K]
// ---------------------------------------------------------------------------
__global__ __launch_bounds__(256) void wtrans(
    const float* __restrict__ W, unsigned short* __restrict__ Wt,
    int K, int N) {
  __shared__ unsigned short tile[32][33];
  int bx = blockIdx.x * 32;
  int by = blockIdx.y * 32;
  int tx = threadIdx.x & 31, ty = threadIdx.x >> 5;
#pragma unroll
  for (int i = 0; i < 32; i += 8)
    tile[ty + i][tx] = f2bf(W[(size_t)(by + ty + i) * N + bx + tx]);
  __syncthreads();
#pragma unroll
  for (int i = 0; i < 32; i += 8)
    Wt[(size_t)(bx + ty + i) * K + by + tx] = tile[tx][ty + i];
}

// ---------------------------------------------------------------------------
// Kernel 3: fused QKV+gate bf16 MFMA GEMM. A[4096,1024] @ Wcat[4096,1024]^T.
// 128x128 tile, BK=32, 4 waves; register-prefetch of next K-chunk overlaps
// the MFMA body. N=4096 sections (wave-uniform per 64-col window):
//   [0,1024)    q    -> qkb[token][col], scaled by QSCALE (after bias)
//   [1024,2048) k    -> qkb[token][col]
//   [2048,3072) v    -> vT[(b*16+h)*64+d][s]  (transposed for attention)
//   [3072,4096) gate -> SiLU -> ub[token][col-3072]
// ---------------------------------------------------------------------------
__global__ __launch_bounds__(256) void gemm_qkvg(
    const unsigned short* __restrict__ A, const unsigned short* __restrict__ Bt,
    const float* __restrict__ bqkv, const float* __restrict__ bgate,
    unsigned short* __restrict__ qkb, unsigned short* __restrict__ vTb,
    unsigned short* __restrict__ ub) {
  __shared__ unsigned short As[128 * 32];
  __shared__ unsigned short Bs[128 * 32];
  const int K = 1024;
  int tid = threadIdx.x;
  int wave = tid >> 6, lane = tid & 63;
  int quad = lane >> 4, m16 = lane & 15;
  int wm = wave >> 1, wn = wave & 1;
  int m0 = blockIdx.y * 128, n0 = blockIdx.x * 128;

  int lrow = tid >> 2;
  int lcol = (tid & 3) * 8;
  const unsigned short* Ar0 = A + (size_t)(m0 + lrow) * K + lcol;
  const unsigned short* Ar1 = A + (size_t)(m0 + lrow + 64) * K + lcol;
  const unsigned short* Br0 = Bt + (size_t)(n0 + lrow) * K + lcol;
  const unsigned short* Br1 = Bt + (size_t)(n0 + lrow + 64) * K + lcol;

  f32x4 acc[4][4];
#pragma unroll
  for (int i = 0; i < 4; ++i)
#pragma unroll
    for (int j = 0; j < 4; ++j) acc[i][j] = (f32x4){0.f, 0.f, 0.f, 0.f};

  uint4 a0 = *(const uint4*)Ar0;
  uint4 a1 = *(const uint4*)Ar1;
  uint4 b0 = *(const uint4*)Br0;
  uint4 b1 = *(const uint4*)Br1;

  for (int k0 = 0; k0 < K; k0 += 32) {
    __syncthreads();
    *(uint4*)&As[lrow * 32 + lcol] = a0;
    *(uint4*)&As[(lrow + 64) * 32 + lcol] = a1;
    *(uint4*)&Bs[lrow * 32 + lcol] = b0;
    *(uint4*)&Bs[(lrow + 64) * 32 + lcol] = b1;
    __syncthreads();
    if (k0 + 32 < K) {  // prefetch next chunk; latency overlaps MFMA below
      a0 = *(const uint4*)(Ar0 + k0 + 32);
      a1 = *(const uint4*)(Ar1 + k0 + 32);
      b0 = *(const uint4*)(Br0 + k0 + 32);
      b1 = *(const uint4*)(Br1 + k0 + 32);
    }
    short8 af[4], bfr[4];
#pragma unroll
    for (int mi = 0; mi < 4; ++mi)
      af[mi] = *(const short8*)&As[(wm * 64 + mi * 16 + m16) * 32 + quad * 8];
#pragma unroll
    for (int ni = 0; ni < 4; ++ni)
      bfr[ni] = *(const short8*)&Bs[(wn * 64 + ni * 16 + m16) * 32 + quad * 8];
#pragma unroll
    for (int mi = 0; mi < 4; ++mi)
#pragma unroll
      for (int ni = 0; ni < 4; ++ni)
        acc[mi][ni] = __builtin_amdgcn_mfma_f32_16x16x32_bf16(
            af[mi], bfr[ni], acc[mi][ni], 0, 0, 0);
  }

  int nwin = n0 + wn * 64;      // 64-col window base (wave-uniform)
  int sec = nwin >> 10;         // 0=q 1=k 2=v 3=gate
  if (sec <= 1) {
    float qs = (sec == 0) ? QSCALE : 1.0f;
#pragma unroll
    for (int ni = 0; ni < 4; ++ni) {
      int col = nwin + ni * 16 + m16;
      float bb = bqkv[col];
#pragma unroll
      for (int mi = 0; mi < 4; ++mi)
#pragma unroll
        for (int r = 0; r < 4; ++r) {
          int row = m0 + wm * 64 + mi * 16 + quad * 4 + r;
          qkb[(size_t)row * 2048 + col] = f2bf((acc[mi][ni][r] + bb) * qs);
        }
    }
  } else if (sec == 2) {
#pragma unroll
    for (int ni = 0; ni < 4; ++ni) {
      int col = nwin + ni * 16 + m16;
      float bb = bqkv[col];
      int vcol = col - 2048;
      int hh = vcol >> 6, dd = vcol & 63;
#pragma unroll
      for (int mi = 0; mi < 4; ++mi) {
        int row0 = m0 + wm * 64 + mi * 16 + quad * 4;
        int bat = row0 >> 11, s0 = row0 & 2047;
        ushort4 o;
        o.x = f2bf(acc[mi][ni][0] + bb);
        o.y = f2bf(acc[mi][ni][1] + bb);
        o.z = f2bf(acc[mi][ni][2] + bb);
        o.w = f2bf(acc[mi][ni][3] + bb);
        *(ushort4*)&vTb[(size_t)((bat * 16 + hh) * 64 + dd) * 2048 + s0] = o;
      }
    }
  } else {
#pragma unroll
    for (int ni = 0; ni < 4; ++ni) {
      int col = nwin + ni * 16 + m16;
      int g = col - 3072;
      float bb = bgate[g];
#pragma unroll
      for (int mi = 0; mi < 4; ++mi)
#pragma unroll
        for (int r = 0; r < 4; ++r) {
          int row = m0 + wm * 64 + mi * 16 + quad * 4 + r;
          float v = acc[mi][ni][r] + bb;
          v = v * __builtin_amdgcn_rcpf(1.0f + exp2f(-v * LOG2E));  // SiLU
          ub[(size_t)row * 1024 + g] = f2bf(v);
        }
    }
  }
}

// ---------------------------------------------------------------------------
// Kernel 4: output GEMM: prod[4096,1024] @ wout[1024,1024]^T + b + x -> f32
// Register-prefetch as above.
// ---------------------------------------------------------------------------
__global__ __launch_bounds__(256) void gemm_out(
    const unsigned short* __restrict__ A, const unsigned short* __restrict__ Bt,
    const float* __restrict__ bias, const float* __restrict__ resid,
    float* __restrict__ C) {
  __shared__ unsigned short As[128 * 32];
  __shared__ unsigned short Bs[128 * 32];
  const int K = 1024, N = 1024;
  int tid = threadIdx.x;
  int wave = tid >> 6, lane = tid & 63;
  int quad = lane >> 4, m16 = lane & 15;
  int wm = wave >> 1, wn = wave & 1;
  int m0 = blockIdx.y * 128, n0 = blockIdx.x * 128;
  int lrow = tid >> 2;
  int lcol = (tid & 3) * 8;
  const unsigned short* Ar0 = A + (size_t)(m0 + lrow) * K + lcol;
  const unsigned short* Ar1 = A + (size_t)(m0 + lrow + 64) * K + lcol;
  const unsigned short* Br0 = Bt + (size_t)(n0 + lrow) * K + lcol;
  const unsigned short* Br1 = Bt + (size_t)(n0 + lrow + 64) * K + lcol;

  f32x4 acc[4][4];
#pragma unroll
  for (int i = 0; i < 4; ++i)
#pragma unroll
    for (int j = 0; j < 4; ++j) acc[i][j] = (f32x4){0.f, 0.f, 0.f, 0.f};

  uint4 a0 = *(const uint4*)Ar0;
  uint4 a1 = *(const uint4*)Ar1;
  uint4 b0 = *(const uint4*)Br0;
  uint4 b1 = *(const uint4*)Br1;

  for (int k0 = 0; k0 < K; k0 += 32) {
    __syncthreads();
    *(uint4*)&As[lrow * 32 + lcol] = a0;
    *(uint4*)&As[(lrow + 64) * 32 + lcol] = a1;
    *(uint4*)&Bs[lrow * 32 + lcol] = b0;
    *(uint4*)&Bs[(lrow + 64) * 32 + lcol] = b1;
    __syncthreads();
    if (k0 + 32 < K) {
      a0 = *(const uint4*)(Ar0 + k0 + 32);
      a1 = *(const uint4*)(Ar1 + k0 + 32);
      b0 = *(const uint4*)(Br0 + k0 + 32);
      b1 = *(const uint4*)(Br1 + k0 + 32);
    }
    short8 af[4], bfr[4];
#pragma unroll
    for (int mi = 0; mi < 4; ++mi)
      af[mi] = *(const short8*)&As[(wm * 64 + mi * 16 + m16) * 32 + quad * 8];
#pragma unroll
    for (int ni = 0; ni < 4; ++ni)
      bfr[ni] = *(const short8*)&Bs[(wn * 64 + ni * 16 + m16) * 32 + quad * 8];
#pragma unroll
    for (int mi = 0; mi < 4; ++mi)
#pragma unroll
      for (int ni = 0; ni < 4; ++ni)
        acc[mi][ni] = __builtin_amdgcn_mfma_f32_16x16x32_bf16(
            af[mi], bfr[ni], acc[mi][ni], 0, 0, 0);
  }
#pragma unroll
  for (int ni = 0; ni < 4; ++ni) {
    int col = n0 + wn * 64 + ni * 16 + m16;
    float bb = bias[col];
#pragma unroll
    for (int mi = 0; mi < 4; ++mi)
#pragma unroll
      for (int r = 0; r < 4; ++r) {
        int row = m0 + wm * 64 + mi * 16 + quad * 4 + r;
        C[(size_t)row * N + col] =
            acc[mi][ni][r] + bb + resid[(size_t)row * N + col];
      }
  }
}

// ---------------------------------------------------------------------------
// Kernel 5: MFMA sigmoid attention, causal, paired q-tiles + fused *u.
// Block = (b,h,pair): q-tiles qtA=blockIdx.x (0..15) and qtB=31-qtA.
// Every block does exactly 33 tile-computes (balanced); each staged K/V
// tile serves both q-tiles. SIMPLE 2-barrier staging per k-iter (the
// proven round-6 structure — no LDS double-buffer).
// qk: [B*S][2048] (q pre-scaled | k), vT: [(b*16+h)*64+d][s],
// u/prod: bf16 [B*S][1024].
// ---------------------------------------------------------------------------
__global__ __launch_bounds__(256) void attn_mfma(
    const unsigned short* __restrict__ qk, const unsigned short* __restrict__ vT,
    const unsigned short* __restrict__ u, const float* __restrict__ rpb,
    unsigned short* __restrict__ prod) {
  __shared__ unsigned short Qs[128 * 72];  // rows 0-63: qtA, 64-127: qtB
  __shared__ unsigned short Ks[64 * 72];
  __shared__ unsigned short Vs[64 * 72];   // Vt[d][key]
  __shared__ unsigned short Ps[64 * 72];   // wave-private rows

  int qtA = blockIdx.x;         // 0..15
  int qtB = 31 - qtA;           // 16..31
  int q0A = qtA * 64, q0B = qtB * 64;
  int bh = blockIdx.y;
  int b = bh >> 4, h = bh & 15;
  int t = threadIdx.x;
  int wave = t >> 6, lane = t & 63;
  int quad = lane >> 4, m16 = lane & 15;

  const unsigned short* qbase = qk + (size_t)(b * SS) * 2048 + h * 64;
  const unsigned short* kbase = qbase + 1024;
  const unsigned short* vbase = vT + (size_t)bh * 64 * 2048;

  int row = t >> 3, blk8 = (t & 7) * 8;  // staging coords (32 rows x 64 cols)

  // load both Q tiles (once)
  {
    const unsigned short* sA = qbase + (size_t)(q0A + row) * 2048 + blk8;
    const unsigned short* sB = qbase + (size_t)(q0B + row) * 2048 + blk8;
    *(uint4*)&Qs[row * 72 + blk8] = *(const uint4*)sA;
    *(uint4*)&Qs[(row + 32) * 72 + blk8] = *(const uint4*)(sA + (size_t)32 * 2048);
    *(uint4*)&Qs[(row + 64) * 72 + blk8] = *(const uint4*)sB;
    *(uint4*)&Qs[(row + 96) * 72 + blk8] = *(const uint4*)(sB + (size_t)32 * 2048);
  }

  f32x4 zero4 = {0.f, 0.f, 0.f, 0.f};
  f32x4 caccA[4], caccB[4];
#pragma unroll
  for (int nb = 0; nb < 4; ++nb) { caccA[nb] = zero4; caccB[nb] = zero4; }

  float hb2 = rpb[h] * LOG2E;
  int ktmax = qtB;

  for (int kt = 0; kt <= ktmax; ++kt) {
    int k0 = kt * 64;
    const unsigned short* kp = kbase + (size_t)(k0 + row) * 2048 + blk8;
    const unsigned short* vp = vbase + (size_t)row * 2048 + k0 + blk8;
    uint4 kv0 = *(const uint4*)kp;
    uint4 kv1 = *(const uint4*)(kp + (size_t)32 * 2048);
    uint4 vv0 = *(const uint4*)vp;
    uint4 vv1 = *(const uint4*)(vp + (size_t)32 * 2048);
    __syncthreads();  // prev-iter readers done (covers Qs on iter 0)
    *(uint4*)&Ks[row * 72 + blk8] = kv0;
    *(uint4*)&Ks[(row + 32) * 72 + blk8] = kv1;
    *(uint4*)&Vs[row * 72 + blk8] = vv0;
    *(uint4*)&Vs[(row + 32) * 72 + blk8] = vv1;
    __syncthreads();

    // ---- tile B (active every iter), then tile A (while kt <= qtA) ----
#pragma unroll
    for (int tile = 0; tile < 2; ++tile) {
      if (tile == 1 && kt > qtA) break;
      int qlds = (tile == 0) ? (64 + wave * 16) : (wave * 16);
      int q0 = (tile == 0) ? q0B : q0A;
      bool diag = (tile == 0) ? (kt == qtB) : (kt == qtA);
      f32x4* cacc = (tile == 0) ? caccB : caccA;

      f32x4 sacc[4];
#pragma unroll
      for (int nb = 0; nb < 4; ++nb) sacc[nb] = zero4;
#pragma unroll
      for (int s = 0; s < 2; ++s) {
        short8 a = *(const short8*)&Qs[(qlds + m16) * 72 + s * 32 + quad * 8];
#pragma unroll
        for (int nb = 0; nb < 4; ++nb) {
          short8 bf = *(const short8*)&Ks[(nb * 16 + m16) * 72 + s * 32 + quad * 8];
          sacc[nb] = __builtin_amdgcn_mfma_f32_16x16x32_bf16(a, bf, sacc[nb], 0, 0, 0);
        }
      }
#pragma unroll
      for (int nb = 0; nb < 4; ++nb) {
#pragma unroll
        for (int r = 0; r < 4; ++r) {
          float y = sacc[nb][r] + hb2;
          float p = __builtin_amdgcn_rcpf(1.0f + exp2f(-y));
          if (diag) {
            int key = k0 + nb * 16 + m16;
            int q = q0 + wave * 16 + quad * 4 + r;
            if (key > q) p = 0.f;
          }
          Ps[(wave * 16 + quad * 4 + r) * 72 + nb * 16 + m16] = f2bf_fast(p);
        }
      }
      // no barrier: wave reads only its own Ps rows (in-wave LDS ordering)
#pragma unroll
      for (int s = 0; s < 2; ++s) {
        short8 a = *(const short8*)&Ps[(wave * 16 + m16) * 72 + s * 32 + quad * 8];
#pragma unroll
        for (int nb = 0; nb < 4; ++nb) {
          short8 bf = *(const short8*)&Vs[(nb * 16 + m16) * 72 + s * 32 + quad * 8];
          cacc[nb] = __builtin_amdgcn_mfma_f32_16x16x32_bf16(a, bf, cacc[nb], 0, 0, 0);
        }
      }
    }
  }

  // epilogue: prod = bf16(ctx * u), layout [token][h*64+d], both tiles
  const unsigned short* ub_ = u + (size_t)(b * SS) * 1024 + h * 64;
  unsigned short* pb_ = prod + (size_t)(b * SS) * 1024 + h * 64;
#pragma unroll
  for (int nb = 0; nb < 4; ++nb) {
    int d = nb * 16 + m16;
#pragma unroll
    for (int r = 0; r < 4; ++r) {
      int qA = q0A + wave * 16 + quad * 4 + r;
      int qB = q0B + wave * 16 + quad * 4 + r;
      pb_[(size_t)qA * 1024 + d] = f2bf(caccA[nb][r] * bf2f(ub_[(size_t)qA * 1024 + d]));
      pb_[(size_t)qB * 1024 + d] = f2bf(caccB[nb][r] * bf2f(ub_[(size_t)qB * 1024 + d]));
    }
  }
}

// ---------------------------------------------------------------------------
extern "C" void kernel_launch(void* const* d_in, const int* in_sizes, int n_in,
                              void* d_out, int out_size, void* d_ws, size_t ws_size,
                              hipStream_t stream) {
  const float* x      = (const float*)d_in[0];
  // d_in[1] = attention_mask (causal tril) — computed analytically, not read
  const float* gamma  = (const float*)d_in[2];
  const float* beta   = (const float*)d_in[3];
  const float* w_qkv  = (const float*)d_in[4];
  const float* b_qkv  = (const float*)d_in[5];
  const float* w_gate = (const float*)d_in[6];
  const float* b_gate = (const float*)d_in[7];
  const float* w_out  = (const float*)d_in[8];
  const float* b_out  = (const float*)d_in[9];
  const float* rpb    = (const float*)d_in[10];
  float* out = (float*)d_out;

  unsigned short* xnb   = (unsigned short*)d_ws;  // 4096*1024
  unsigned short* qkb   = xnb + 4194304;          // 4096*2048 (q|k)
  unsigned short* vTb   = qkb + 8388608;          // 32*64*2048
  unsigned short* ub    = vTb + 4194304;          // 4096*1024
  unsigned short* prodb = ub + 4194304;           // 4096*1024
  unsigned short* wcatT = prodb + 4194304;        // 4096*1024 (qkv|gate rows)
  unsigned short* woutT = wcatT + 4194304;        // 1024*1024
  // total ~60 MB

  // 1. LayerNorm -> bf16
  ln_kernel<<<BB * SS, 256, 0, stream>>>(x, gamma, beta, xnb);
  // 2. Weight transposes fp32[K][N] -> bf16[N][K]; gate rows appended at 3072
  wtrans<<<dim3(3072 / 32, 1024 / 32), 256, 0, stream>>>(w_qkv, wcatT, 1024, 3072);
  wtrans<<<dim3(1024 / 32, 1024 / 32), 256, 0, stream>>>(w_gate, wcatT + (size_t)3072 * 1024, 1024, 1024);
  wtrans<<<dim3(1024 / 32, 1024 / 32), 256, 0, stream>>>(w_out, woutT, 1024, 1024);
  // 3. Fused QKV+gate GEMM: N=4096 sections -> qkb, vTb, ub
  gemm_qkvg<<<dim3(4096 / 128, 4096 / 128), 256, 0, stream>>>(
      xnb, wcatT, b_qkv, b_gate, qkb, vTb, ub);
  // 4. MFMA sigmoid attention (paired q-tiles, balanced) + fused *u -> prodb
  attn_mfma<<<dim3(16, BB * HH), 256, 0, stream>>>(qkb, vTb, ub, rpb, prodb);
  // 5. Output projection: prod @ w_out + b_out + x -> f32 out
  gemm_out<<<dim3(1024 / 128, 4096 / 128), 256, 0, stream>>>(
      prodb, woutT, b_out, x, out);
}

// Round 9
// 251.124 us; speedup vs baseline: 17.7904x; 1.0122x over previous
//
#include <hip/hip_runtime.h>
#include <hip/hip_bf16.h>
#include <cmath>

// Problem constants (HSTU layer): B=2, S=2048, D=1024, H=16, HD=64
#define BB 2
#define SS 2048
#define DD 1024
#define HH 16
#define EPS 1e-5f
#define LOG2E 1.44269504088896f
#define QSCALE (0.125f * LOG2E)   // HD^-0.5 * log2(e), folded into q

typedef __attribute__((ext_vector_type(8))) short short8;   // 8 bf16 (4 VGPRs)
typedef __attribute__((ext_vector_type(4))) float f32x4;    // 4 fp32 acc

__device__ inline unsigned short f2bf(float f) {
  union { float f; unsigned int u; } v; v.f = f;
  unsigned int u = v.u;
  unsigned int r = (u + 0x7FFFu + ((u >> 16) & 1u)) >> 16;  // RNE
  return (unsigned short)r;
}
__device__ inline float bf2f(unsigned short h) {
  union { unsigned int u; float f; } v; v.u = ((unsigned int)h) << 16;
  return v.f;
}
// fast pack: round-half-up (differs from RNE only at exact ties)
__device__ inline unsigned short f2bf_fast(float f) {
  union { float f; unsigned int u; } v; v.f = f;
  return (unsigned short)((v.u + 0x8000u) >> 16);
}

// ---------------------------------------------------------------------------
// Kernel 1: LayerNorm over D=1024, bf16 output. One block (256 thr) per row.
// ---------------------------------------------------------------------------
__global__ __launch_bounds__(256) void ln_kernel(
    const float* __restrict__ x, const float* __restrict__ gamma,
    const float* __restrict__ beta, unsigned short* __restrict__ xn) {
  int row = blockIdx.x;
  int t = threadIdx.x;
  const float* xr = x + (size_t)row * DD;
  float4 v = *(const float4*)(xr + t * 4);
  float s = v.x + v.y + v.z + v.w;
  float sq = v.x * v.x + v.y * v.y + v.z * v.z + v.w * v.w;
  for (int off = 32; off > 0; off >>= 1) {
    s += __shfl_down(s, off, 64);
    sq += __shfl_down(sq, off, 64);
  }
  __shared__ float ls[4], lq[4];
  int wave = t >> 6, lane = t & 63;
  if (lane == 0) { ls[wave] = s; lq[wave] = sq; }
  __syncthreads();
  float tot = ls[0] + ls[1] + ls[2] + ls[3];
  float totq = lq[0] + lq[1] + lq[2] + lq[3];
  float mu = tot * (1.0f / DD);
  float var = totq * (1.0f / DD) - mu * mu;
  float rstd = rsqrtf(var + EPS);
  float4 g = *(const float4*)(gamma + t * 4);
  float4 bt = *(const float4*)(beta + t * 4);
  ushort4 o;
  o.x = f2bf((v.x - mu) * rstd * g.x + bt.x);
  o.y = f2bf((v.y - mu) * rstd * g.y + bt.y);
  o.z = f2bf((v.z - mu) * rstd * g.z + bt.z);
  o.w = f2bf((v.w - mu) * rstd * g.w + bt.w);
  *(ushort4*)(xn + (size_t)row * DD + t * 4) = o;
}

// ---------------------------------------------------------------------------
// Kernel 2: merged transpose+cast: fp32 W[1024][N] -> bf16 Wt[N][1024]
// for w_qkv (->wcatT rows 0-3071), w_gate (->wcatT rows 3072-4095),
// w_out (->woutT). grid (160, 32).
// ---------------------------------------------------------------------------
__global__ __launch_bounds__(256) void wtrans_all(
    const float* __restrict__ wq, const float* __restrict__ wg,
    const float* __restrict__ wo, unsigned short* __restrict__ wcatT,
    unsigned short* __restrict__ woutT) {
  __shared__ unsigned short tile[32][33];
  int bx = blockIdx.x;  // 0..159
  const float* W;
  unsigned short* Wt;
  int N, colbase;
  if (bx < 96)       { W = wq; Wt = wcatT; N = 3072; colbase = bx * 32; }
  else if (bx < 128) { W = wg; Wt = wcatT + (size_t)3072 * 1024; N = 1024; colbase = (bx - 96) * 32; }
  else               { W = wo; Wt = woutT; N = 1024; colbase = (bx - 128) * 32; }
  int by = blockIdx.y * 32;  // K rows
  int tx = threadIdx.x & 31, ty = threadIdx.x >> 5;
#pragma unroll
  for (int i = 0; i < 32; i += 8)
    tile[ty + i][tx] = f2bf(W[(size_t)(by + ty + i) * N + colbase + tx]);
  __syncthreads();
#pragma unroll
  for (int i = 0; i < 32; i += 8)
    Wt[(size_t)(colbase + ty + i) * 1024 + by + tx] = tile[tx][ty + i];
}

// ---------------------------------------------------------------------------
// Kernel 3: fused QKV+gate bf16 MFMA GEMM. A[4096,1024] @ Wcat[4096,1024]^T.
// 128x128 tile, BK=32, 4 waves; register-prefetch. Sections (block-uniform):
//   [0,1024)    q    -> qkb[token][col], scaled by QSCALE (after bias)
//   [1024,2048) k    -> qkb[token][col]
//   [2048,3072) v    -> vT[(b*16+h)*64+d][s], via LDS transpose (coalesced)
//   [3072,4096) gate -> SiLU -> ub[token][col-3072]
// ---------------------------------------------------------------------------
__global__ __launch_bounds__(256) void gemm_qkvg(
    const unsigned short* __restrict__ A, const unsigned short* __restrict__ Bt,
    const float* __restrict__ bqkv, const float* __restrict__ bgate,
    unsigned short* __restrict__ qkb, unsigned short* __restrict__ vTb,
    unsigned short* __restrict__ ub) {
  __shared__ unsigned short SH[128 * 64];  // As | Bs; reused for v transpose
  unsigned short* As = SH;                 // 128*32
  unsigned short* Bs = SH + 128 * 32;      // 128*32
  const int K = 1024;
  int tid = threadIdx.x;
  int wave = tid >> 6, lane = tid & 63;
  int quad = lane >> 4, m16 = lane & 15;
  int wm = wave >> 1, wn = wave & 1;
  int m0 = blockIdx.y * 128, n0 = blockIdx.x * 128;

  int lrow = tid >> 2;
  int lcol = (tid & 3) * 8;
  const unsigned short* Ar0 = A + (size_t)(m0 + lrow) * K + lcol;
  const unsigned short* Ar1 = A + (size_t)(m0 + lrow + 64) * K + lcol;
  const unsigned short* Br0 = Bt + (size_t)(n0 + lrow) * K + lcol;
  const unsigned short* Br1 = Bt + (size_t)(n0 + lrow + 64) * K + lcol;

  f32x4 acc[4][4];
#pragma unroll
  for (int i = 0; i < 4; ++i)
#pragma unroll
    for (int j = 0; j < 4; ++j) acc[i][j] = (f32x4){0.f, 0.f, 0.f, 0.f};

  uint4 a0 = *(const uint4*)Ar0;
  uint4 a1 = *(const uint4*)Ar1;
  uint4 b0 = *(const uint4*)Br0;
  uint4 b1 = *(const uint4*)Br1;

  for (int k0 = 0; k0 < K; k0 += 32) {
    __syncthreads();
    *(uint4*)&As[lrow * 32 + lcol] = a0;
    *(uint4*)&As[(lrow + 64) * 32 + lcol] = a1;
    *(uint4*)&Bs[lrow * 32 + lcol] = b0;
    *(uint4*)&Bs[(lrow + 64) * 32 + lcol] = b1;
    __syncthreads();
    if (k0 + 32 < K) {  // prefetch next chunk; latency overlaps MFMA below
      a0 = *(const uint4*)(Ar0 + k0 + 32);
      a1 = *(const uint4*)(Ar1 + k0 + 32);
      b0 = *(const uint4*)(Br0 + k0 + 32);
      b1 = *(const uint4*)(Br1 + k0 + 32);
    }
    short8 af[4], bfr[4];
#pragma unroll
    for (int mi = 0; mi < 4; ++mi)
      af[mi] = *(const short8*)&As[(wm * 64 + mi * 16 + m16) * 32 + quad * 8];
#pragma unroll
    for (int ni = 0; ni < 4; ++ni)
      bfr[ni] = *(const short8*)&Bs[(wn * 64 + ni * 16 + m16) * 32 + quad * 8];
#pragma unroll
    for (int mi = 0; mi < 4; ++mi)
#pragma unroll
      for (int ni = 0; ni < 4; ++ni)
        acc[mi][ni] = __builtin_amdgcn_mfma_f32_16x16x32_bf16(
            af[mi], bfr[ni], acc[mi][ni], 0, 0, 0);
  }

  int sec = n0 >> 10;  // block-uniform: 0=q 1=k 2=v 3=gate
  if (sec == 2) {
    // ---- v section: LDS transpose -> coalesced vT[(b*16+h)*64+d][s] ----
    int bat = m0 >> 11;
    int s_base = m0 & 2047;     // 128-tile never crosses batch boundary
    int dgbase = n0 - 2048;     // 128-aligned v column base
#pragma unroll
    for (int p = 0; p < 2; ++p) {
      __syncthreads();  // SH free (MFMA reads / prev-pass reads done)
      if (wn == p) {
#pragma unroll
        for (int ni = 0; ni < 4; ++ni) {
          int dl = ni * 16 + m16;                 // 0..63
          float bb = bqkv[2048 + dgbase + p * 64 + dl];
#pragma unroll
          for (int mi = 0; mi < 4; ++mi)
#pragma unroll
            for (int r = 0; r < 4; ++r) {
              int sl = wm * 64 + mi * 16 + quad * 4 + r;   // 0..127
              int sls = sl ^ ((dl & 7) << 4);              // bank swizzle
              SH[dl * 128 + sls] = f2bf(acc[mi][ni][r] + bb);
            }
        }
      }
      __syncthreads();
      int dl = tid >> 2;                    // 0..63
      int dg = dgbase + p * 64 + dl;        // global v col 0..1023
      unsigned short* dst =
          vTb + ((size_t)(bat * 16 + (dg >> 6)) * 64 + (dg & 63)) * 2048 + s_base;
#pragma unroll
      for (int i = 0; i < 4; ++i) {
        int s0 = (tid & 3) * 8 + i * 32;
        int s0s = s0 ^ ((dl & 7) << 4);
        *(uint4*)(dst + s0) = *(const uint4*)&SH[dl * 128 + s0s];
      }
    }
  } else {
    int nwin = n0 + wn * 64;
    if (sec <= 1) {
      float qs = (sec == 0) ? QSCALE : 1.0f;
#pragma unroll
      for (int ni = 0; ni < 4; ++ni) {
        int col = nwin + ni * 16 + m16;
        float bb = bqkv[col];
#pragma unroll
        for (int mi = 0; mi < 4; ++mi)
#pragma unroll
          for (int r = 0; r < 4; ++r) {
            int row = m0 + wm * 64 + mi * 16 + quad * 4 + r;
            qkb[(size_t)row * 2048 + col] = f2bf((acc[mi][ni][r] + bb) * qs);
          }
      }
    } else {
#pragma unroll
      for (int ni = 0; ni < 4; ++ni) {
        int col = nwin + ni * 16 + m16;
        int g = col - 3072;
        float bb = bgate[g];
#pragma unroll
        for (int mi = 0; mi < 4; ++mi)
#pragma unroll
          for (int r = 0; r < 4; ++r) {
            int row = m0 + wm * 64 + mi * 16 + quad * 4 + r;
            float v = acc[mi][ni][r] + bb;
            v = v * __builtin_amdgcn_rcpf(1.0f + exp2f(-v * LOG2E));  // SiLU
            ub[(size_t)row * 1024 + g] = f2bf(v);
          }
      }
    }
  }
}

// ---------------------------------------------------------------------------
// Kernel 4: output GEMM: prod[4096,1024] @ wout[1024,1024]^T + b + x -> f32
// ---------------------------------------------------------------------------
__global__ __launch_bounds__(256) void gemm_out(
    const unsigned short* __restrict__ A, const unsigned short* __restrict__ Bt,
    const float* __restrict__ bias, const float* __restrict__ resid,
    float* __restrict__ C) {
  __shared__ unsigned short As[128 * 32];
  __shared__ unsigned short Bs[128 * 32];
  const int K = 1024, N = 1024;
  int tid = threadIdx.x;
  int wave = tid >> 6, lane = tid & 63;
  int quad = lane >> 4, m16 = lane & 15;
  int wm = wave >> 1, wn = wave & 1;
  int m0 = blockIdx.y * 128, n0 = blockIdx.x * 128;
  int lrow = tid >> 2;
  int lcol = (tid & 3) * 8;
  const unsigned short* Ar0 = A + (size_t)(m0 + lrow) * K + lcol;
  const unsigned short* Ar1 = A + (size_t)(m0 + lrow + 64) * K + lcol;
  const unsigned short* Br0 = Bt + (size_t)(n0 + lrow) * K + lcol;
  const unsigned short* Br1 = Bt + (size_t)(n0 + lrow + 64) * K + lcol;

  f32x4 acc[4][4];
#pragma unroll
  for (int i = 0; i < 4; ++i)
#pragma unroll
    for (int j = 0; j < 4; ++j) acc[i][j] = (f32x4){0.f, 0.f, 0.f, 0.f};

  uint4 a0 = *(const uint4*)Ar0;
  uint4 a1 = *(const uint4*)Ar1;
  uint4 b0 = *(const uint4*)Br0;
  uint4 b1 = *(const uint4*)Br1;

  for (int k0 = 0; k0 < K; k0 += 32) {
    __syncthreads();
    *(uint4*)&As[lrow * 32 + lcol] = a0;
    *(uint4*)&As[(lrow + 64) * 32 + lcol] = a1;
    *(uint4*)&Bs[lrow * 32 + lcol] = b0;
    *(uint4*)&Bs[(lrow + 64) * 32 + lcol] = b1;
    __syncthreads();
    if (k0 + 32 < K) {
      a0 = *(const uint4*)(Ar0 + k0 + 32);
      a1 = *(const uint4*)(Ar1 + k0 + 32);
      b0 = *(const uint4*)(Br0 + k0 + 32);
      b1 = *(const uint4*)(Br1 + k0 + 32);
    }
    short8 af[4], bfr[4];
#pragma unroll
    for (int mi = 0; mi < 4; ++mi)
      af[mi] = *(const short8*)&As[(wm * 64 + mi * 16 + m16) * 32 + quad * 8];
#pragma unroll
    for (int ni = 0; ni < 4; ++ni)
      bfr[ni] = *(const short8*)&Bs[(wn * 64 + ni * 16 + m16) * 32 + quad * 8];
#pragma unroll
    for (int mi = 0; mi < 4; ++mi)
#pragma unroll
      for (int ni = 0; ni < 4; ++ni)
        acc[mi][ni] = __builtin_amdgcn_mfma_f32_16x16x32_bf16(
            af[mi], bfr[ni], acc[mi][ni], 0, 0, 0);
  }
#pragma unroll
  for (int ni = 0; ni < 4; ++ni) {
    int col = n0 + wn * 64 + ni * 16 + m16;
    float bb = bias[col];
#pragma unroll
    for (int mi = 0; mi < 4; ++mi)
#pragma unroll
      for (int r = 0; r < 4; ++r) {
        int row = m0 + wm * 64 + mi * 16 + quad * 4 + r;
        C[(size_t)row * N + col] =
            acc[mi][ni][r] + bb + resid[(size_t)row * N + col];
      }
  }
}

// ---------------------------------------------------------------------------
// Kernel 5: MFMA sigmoid attention, causal, paired q-tiles + fused *u.
// Block = (b,h,pair): q-tiles qtA=blockIdx.x (0..15) and qtB=31-qtA (33
// tile-computes per block, balanced). 2-barrier staging per k-iter.
// K/V fragments hoisted into registers once per k-tile (shared by both
// q-tiles). Ps columns XOR-swizzled by quad -> conflict-free banks.
// ---------------------------------------------------------------------------
__global__ __launch_bounds__(256) void attn_mfma(
    const unsigned short* __restrict__ qk, const unsigned short* __restrict__ vT,
    const unsigned short* __restrict__ u, const float* __restrict__ rpb,
    unsigned short* __restrict__ prod) {
  __shared__ unsigned short Qs[128 * 72];  // rows 0-63: qtA, 64-127: qtB
  __shared__ unsigned short Ks[64 * 72];
  __shared__ unsigned short Vs[64 * 72];   // Vt[d][key]
  __shared__ unsigned short Ps[64 * 72];   // wave-private rows, col-swizzled

  int qtA = blockIdx.x;         // 0..15
  int qtB = 31 - qtA;           // 16..31
  int q0A = qtA * 64, q0B = qtB * 64;
  int bh = blockIdx.y;
  int b = bh >> 4, h = bh & 15;
  int t = threadIdx.x;
  int wave = t >> 6, lane = t & 63;
  int quad = lane >> 4, m16 = lane & 15;

  const unsigned short* qbase = qk + (size_t)(b * SS) * 2048 + h * 64;
  const unsigned short* kbase = qbase + 1024;
  const unsigned short* vbase = vT + (size_t)bh * 64 * 2048;

  int row = t >> 3, blk8 = (t & 7) * 8;  // staging coords (32 rows x 64 cols)

  // load both Q tiles (once)
  {
    const unsigned short* sA = qbase + (size_t)(q0A + row) * 2048 + blk8;
    const unsigned short* sB = qbase + (size_t)(q0B + row) * 2048 + blk8;
    *(uint4*)&Qs[row * 72 + blk8] = *(const uint4*)sA;
    *(uint4*)&Qs[(row + 32) * 72 + blk8] = *(const uint4*)(sA + (size_t)32 * 2048);
    *(uint4*)&Qs[(row + 64) * 72 + blk8] = *(const uint4*)sB;
    *(uint4*)&Qs[(row + 96) * 72 + blk8] = *(const uint4*)(sB + (size_t)32 * 2048);
  }

  f32x4 zero4 = {0.f, 0.f, 0.f, 0.f};
  f32x4 caccA[4], caccB[4];
#pragma unroll
  for (int nb = 0; nb < 4; ++nb) { caccA[nb] = zero4; caccB[nb] = zero4; }

  float hb2 = rpb[h] * LOG2E;
  int ktmax = qtB;
  int psw = quad << 3;                  // Ps write swizzle key
  int psr = ((m16 >> 2) & 3) << 3;      // Ps read un-swizzle key

  for (int kt = 0; kt <= ktmax; ++kt) {
    int k0 = kt * 64;
    const unsigned short* kp = kbase + (size_t)(k0 + row) * 2048 + blk8;
    const unsigned short* vp = vbase + (size_t)row * 2048 + k0 + blk8;
    uint4 kv0 = *(const uint4*)kp;
    uint4 kv1 = *(const uint4*)(kp + (size_t)32 * 2048);
    uint4 vv0 = *(const uint4*)vp;
    uint4 vv1 = *(const uint4*)(vp + (size_t)32 * 2048);
    __syncthreads();  // prev-iter readers done (covers Qs on iter 0)
    *(uint4*)&Ks[row * 72 + blk8] = kv0;
    *(uint4*)&Ks[(row + 32) * 72 + blk8] = kv1;
    *(uint4*)&Vs[row * 72 + blk8] = vv0;
    *(uint4*)&Vs[(row + 32) * 72 + blk8] = vv1;
    __syncthreads();

    // hoisted K/V fragments (shared by both q-tiles)
    short8 kf[2][4], vf[2][4];
#pragma unroll
    for (int s = 0; s < 2; ++s)
#pragma unroll
      for (int nb = 0; nb < 4; ++nb) {
        kf[s][nb] = *(const short8*)&Ks[(nb * 16 + m16) * 72 + s * 32 + quad * 8];
        vf[s][nb] = *(const short8*)&Vs[(nb * 16 + m16) * 72 + s * 32 + quad * 8];
      }

#pragma unroll
    for (int tile = 0; tile < 2; ++tile) {
      if (tile == 1 && kt > qtA) break;
      int qlds = (tile == 0) ? (64 + wave * 16) : (wave * 16);
      int q0 = (tile == 0) ? q0B : q0A;
      bool diag = (tile == 0) ? (kt == qtB) : (kt == qtA);
      f32x4* cacc = (tile == 0) ? caccB : caccA;

      f32x4 sacc[4];
#pragma unroll
      for (int nb = 0; nb < 4; ++nb) sacc[nb] = zero4;
#pragma unroll
      for (int s = 0; s < 2; ++s) {
        short8 a = *(const short8*)&Qs[(qlds + m16) * 72 + s * 32 + quad * 8];
#pragma unroll
        for (int nb = 0; nb < 4; ++nb)
          sacc[nb] = __builtin_amdgcn_mfma_f32_16x16x32_bf16(a, kf[s][nb], sacc[nb], 0, 0, 0);
      }
#pragma unroll
      for (int nb = 0; nb < 4; ++nb) {
#pragma unroll
        for (int r = 0; r < 4; ++r) {
          float y = sacc[nb][r] + hb2;
          float p = __builtin_amdgcn_rcpf(1.0f + exp2f(-y));
          if (diag) {
            int key = k0 + nb * 16 + m16;
            int q = q0 + wave * 16 + quad * 4 + r;
            if (key > q) p = 0.f;
          }
          int colS = (nb * 16 + m16) ^ psw;  // conflict-free bank swizzle
          Ps[(wave * 16 + quad * 4 + r) * 72 + colS] = f2bf_fast(p);
        }
      }
      // no barrier: wave reads only its own Ps rows (in-wave LDS ordering)
#pragma unroll
      for (int s = 0; s < 2; ++s) {
        int pcol = (s * 32 + quad * 8) ^ psr;  // un-swizzle (8-contig, 16B ok)
        short8 a = *(const short8*)&Ps[(wave * 16 + m16) * 72 + pcol];
#pragma unroll
        for (int nb = 0; nb < 4; ++nb)
          cacc[nb] = __builtin_amdgcn_mfma_f32_16x16x32_bf16(a, vf[s][nb], cacc[nb], 0, 0, 0);
      }
    }
  }

  // epilogue: prod = bf16(ctx * u), layout [token][h*64+d], both tiles
  const unsigned short* ub_ = u + (size_t)(b * SS) * 1024 + h * 64;
  unsigned short* pb_ = prod + (size_t)(b * SS) * 1024 + h * 64;
#pragma unroll
  for (int nb = 0; nb < 4; ++nb) {
    int d = nb * 16 + m16;
#pragma unroll
    for (int r = 0; r < 4; ++r) {
      int qA = q0A + wave * 16 + quad * 4 + r;
      int qB = q0B + wave * 16 + quad * 4 + r;
      pb_[(size_t)qA * 1024 + d] = f2bf(caccA[nb][r] * bf2f(ub_[(size_t)qA * 1024 + d]));
      pb_[(size_t)qB * 1024 + d] = f2bf(caccB[nb][r] * bf2f(ub_[(size_t)qB * 1024 + d]));
    }
  }
}

// ---------------------------------------------------------------------------
extern "C" void kernel_launch(void* const* d_in, const int* in_sizes, int n_in,
                              void* d_out, int out_size, void* d_ws, size_t ws_size,
                              hipStream_t stream) {
  const float* x      = (const float*)d_in[0];
  // d_in[1] = attention_mask (causal tril) — computed analytically, not read
  const float* gamma  = (const float*)d_in[2];
  const float* beta   = (const float*)d_in[3];
  const float* w_qkv  = (const float*)d_in[4];
  const float* b_qkv  = (const float*)d_in[5];
  const float* w_gate = (const float*)d_in[6];
  const float* b_gate = (const float*)d_in[7];
  const float* w_out  = (const float*)d_in[8];
  const float* b_out  = (const float*)d_in[9];
  const float* rpb    = (const float*)d_in[10];
  float* out = (float*)d_out;

  unsigned short* xnb   = (unsigned short*)d_ws;  // 4096*1024
  unsigned short* qkb   = xnb + 4194304;          // 4096*2048 (q|k)
  unsigned short* vTb   = qkb + 8388608;          // 32*64*2048
  unsigned short* ub    = vTb + 4194304;          // 4096*1024
  unsigned short* prodb = ub + 4194304;           // 4096*1024
  unsigned short* wcatT = prodb + 4194304;        // 4096*1024 (qkv|gate rows)
  unsigned short* woutT = wcatT + 4194304;        // 1024*1024
  // total ~60 MB

  // 1. LayerNorm -> bf16
  ln_kernel<<<BB * SS, 256, 0, stream>>>(x, gamma, beta, xnb);
  // 2. Merged weight transposes fp32[K][N] -> bf16[N][K]
  wtrans_all<<<dim3(160, 32), 256, 0, stream>>>(w_qkv, w_gate, w_out, wcatT, woutT);
  // 3. Fused QKV+gate GEMM: N=4096 sections -> qkb, vTb (coalesced), ub
  gemm_qkvg<<<dim3(4096 / 128, 4096 / 128), 256, 0, stream>>>(
      xnb, wcatT, b_qkv, b_gate, qkb, vTb, ub);
  // 4. MFMA sigmoid attention (paired q-tiles, hoisted K/V frags) -> prodb
  attn_mfma<<<dim3(16, BB * HH), 256, 0, stream>>>(qkb, vTb, ub, rpb, prodb);
  // 5. Output projection: prod @ w_out + b_out + x -> f32 out
  gemm_out<<<dim3(1024 / 128, 4096 / 128), 256, 0, stream>>>(
      prodb, woutT, b_out, x, out);
}

// Round 10
// 245.070 us; speedup vs baseline: 18.2299x; 1.0247x over previous
//
#include <hip/hip_runtime.h>
#include <hip/hip_bf16.h>
#include <cmath>

// Problem constants (HSTU layer): B=2, S=2048, D=1024, H=16, HD=64
#define BB 2
#define SS 2048
#define DD 1024
#define HH 16
#define EPS 1e-5f
#define LOG2E 1.44269504088896f
#define QSCALE (0.125f * LOG2E)   // HD^-0.5 * log2(e), folded into q

typedef __attribute__((ext_vector_type(8))) short short8;   // 8 bf16 (4 VGPRs)
typedef __attribute__((ext_vector_type(4))) float f32x4;    // 4 fp32 acc

__device__ inline unsigned short f2bf(float f) {
  union { float f; unsigned int u; } v; v.f = f;
  unsigned int u = v.u;
  unsigned int r = (u + 0x7FFFu + ((u >> 16) & 1u)) >> 16;  // RNE
  return (unsigned short)r;
}
__device__ inline float bf2f(unsigned short h) {
  union { unsigned int u; float f; } v; v.u = ((unsigned int)h) << 16;
  return v.f;
}
// fast pack: round-half-up (differs from RNE only at exact ties)
__device__ inline unsigned short f2bf_fast(float f) {
  union { float f; unsigned int u; } v; v.f = f;
  return (unsigned short)((v.u + 0x8000u) >> 16);
}

// ---------------------------------------------------------------------------
// Kernel 1: LayerNorm over D=1024, bf16 output. One block (256 thr) per row.
// ---------------------------------------------------------------------------
__global__ __launch_bounds__(256) void ln_kernel(
    const float* __restrict__ x, const float* __restrict__ gamma,
    const float* __restrict__ beta, unsigned short* __restrict__ xn) {
  int row = blockIdx.x;
  int t = threadIdx.x;
  const float* xr = x + (size_t)row * DD;
  float4 v = *(const float4*)(xr + t * 4);
  float s = v.x + v.y + v.z + v.w;
  float sq = v.x * v.x + v.y * v.y + v.z * v.z + v.w * v.w;
  for (int off = 32; off > 0; off >>= 1) {
    s += __shfl_down(s, off, 64);
    sq += __shfl_down(sq, off, 64);
  }
  __shared__ float ls[4], lq[4];
  int wave = t >> 6, lane = t & 63;
  if (lane == 0) { ls[wave] = s; lq[wave] = sq; }
  __syncthreads();
  float tot = ls[0] + ls[1] + ls[2] + ls[3];
  float totq = lq[0] + lq[1] + lq[2] + lq[3];
  float mu = tot * (1.0f / DD);
  float var = totq * (1.0f / DD) - mu * mu;
  float rstd = rsqrtf(var + EPS);
  float4 g = *(const float4*)(gamma + t * 4);
  float4 bt = *(const float4*)(beta + t * 4);
  ushort4 o;
  o.x = f2bf((v.x - mu) * rstd * g.x + bt.x);
  o.y = f2bf((v.y - mu) * rstd * g.y + bt.y);
  o.z = f2bf((v.z - mu) * rstd * g.z + bt.z);
  o.w = f2bf((v.w - mu) * rstd * g.w + bt.w);
  *(ushort4*)(xn + (size_t)row * DD + t * 4) = o;
}

// ---------------------------------------------------------------------------
// Kernel 2: merged transpose+cast: fp32 W[1024][N] -> bf16 Wt[N][1024]
// ---------------------------------------------------------------------------
__global__ __launch_bounds__(256) void wtrans_all(
    const float* __restrict__ wq, const float* __restrict__ wg,
    const float* __restrict__ wo, unsigned short* __restrict__ wcatT,
    unsigned short* __restrict__ woutT) {
  __shared__ unsigned short tile[32][33];
  int bx = blockIdx.x;  // 0..159
  const float* W;
  unsigned short* Wt;
  int N, colbase;
  if (bx < 96)       { W = wq; Wt = wcatT; N = 3072; colbase = bx * 32; }
  else if (bx < 128) { W = wg; Wt = wcatT + (size_t)3072 * 1024; N = 1024; colbase = (bx - 96) * 32; }
  else               { W = wo; Wt = woutT; N = 1024; colbase = (bx - 128) * 32; }
  int by = blockIdx.y * 32;  // K rows
  int tx = threadIdx.x & 31, ty = threadIdx.x >> 5;
#pragma unroll
  for (int i = 0; i < 32; i += 8)
    tile[ty + i][tx] = f2bf(W[(size_t)(by + ty + i) * N + colbase + tx]);
  __syncthreads();
#pragma unroll
  for (int i = 0; i < 32; i += 8)
    Wt[(size_t)(colbase + ty + i) * 1024 + by + tx] = tile[tx][ty + i];
}

// ---------------------------------------------------------------------------
// Kernel 3: fused QKV+gate bf16 MFMA GEMM. A[4096,1024] @ Wcat[4096,1024]^T.
// 128x128 tile, BK=32, 4 waves; register-prefetch. Sections (block-uniform):
//   [0,1024)    q    -> qkb[token][col], scaled by QSCALE (after bias)
//   [1024,2048) k    -> qkb[token][col]
//   [2048,3072) v    -> vT[(b*16+h)*64+d][s], via LDS transpose (coalesced)
//   [3072,4096) gate -> SiLU -> ub[token][col-3072]
// ---------------------------------------------------------------------------
__global__ __launch_bounds__(256) void gemm_qkvg(
    const unsigned short* __restrict__ A, const unsigned short* __restrict__ Bt,
    const float* __restrict__ bqkv, const float* __restrict__ bgate,
    unsigned short* __restrict__ qkb, unsigned short* __restrict__ vTb,
    unsigned short* __restrict__ ub) {
  __shared__ unsigned short SH[128 * 64];  // As | Bs; reused for v transpose
  unsigned short* As = SH;                 // 128*32
  unsigned short* Bs = SH + 128 * 32;      // 128*32
  const int K = 1024;
  int tid = threadIdx.x;
  int wave = tid >> 6, lane = tid & 63;
  int quad = lane >> 4, m16 = lane & 15;
  int wm = wave >> 1, wn = wave & 1;
  int m0 = blockIdx.y * 128, n0 = blockIdx.x * 128;

  int lrow = tid >> 2;
  int lcol = (tid & 3) * 8;
  const unsigned short* Ar0 = A + (size_t)(m0 + lrow) * K + lcol;
  const unsigned short* Ar1 = A + (size_t)(m0 + lrow + 64) * K + lcol;
  const unsigned short* Br0 = Bt + (size_t)(n0 + lrow) * K + lcol;
  const unsigned short* Br1 = Bt + (size_t)(n0 + lrow + 64) * K + lcol;

  f32x4 acc[4][4];
#pragma unroll
  for (int i = 0; i < 4; ++i)
#pragma unroll
    for (int j = 0; j < 4; ++j) acc[i][j] = (f32x4){0.f, 0.f, 0.f, 0.f};

  uint4 a0 = *(const uint4*)Ar0;
  uint4 a1 = *(const uint4*)Ar1;
  uint4 b0 = *(const uint4*)Br0;
  uint4 b1 = *(const uint4*)Br1;

  for (int k0 = 0; k0 < K; k0 += 32) {
    __syncthreads();
    *(uint4*)&As[lrow * 32 + lcol] = a0;
    *(uint4*)&As[(lrow + 64) * 32 + lcol] = a1;
    *(uint4*)&Bs[lrow * 32 + lcol] = b0;
    *(uint4*)&Bs[(lrow + 64) * 32 + lcol] = b1;
    __syncthreads();
    if (k0 + 32 < K) {  // prefetch next chunk; latency overlaps MFMA below
      a0 = *(const uint4*)(Ar0 + k0 + 32);
      a1 = *(const uint4*)(Ar1 + k0 + 32);
      b0 = *(const uint4*)(Br0 + k0 + 32);
      b1 = *(const uint4*)(Br1 + k0 + 32);
    }
    short8 af[4], bfr[4];
#pragma unroll
    for (int mi = 0; mi < 4; ++mi)
      af[mi] = *(const short8*)&As[(wm * 64 + mi * 16 + m16) * 32 + quad * 8];
#pragma unroll
    for (int ni = 0; ni < 4; ++ni)
      bfr[ni] = *(const short8*)&Bs[(wn * 64 + ni * 16 + m16) * 32 + quad * 8];
#pragma unroll
    for (int mi = 0; mi < 4; ++mi)
#pragma unroll
      for (int ni = 0; ni < 4; ++ni)
        acc[mi][ni] = __builtin_amdgcn_mfma_f32_16x16x32_bf16(
            af[mi], bfr[ni], acc[mi][ni], 0, 0, 0);
  }

  int sec = n0 >> 10;  // block-uniform: 0=q 1=k 2=v 3=gate
  if (sec == 2) {
    // ---- v section: LDS transpose -> coalesced vT[(b*16+h)*64+d][s] ----
    int bat = m0 >> 11;
    int s_base = m0 & 2047;     // 128-tile never crosses batch boundary
    int dgbase = n0 - 2048;     // 128-aligned v column base
#pragma unroll
    for (int p = 0; p < 2; ++p) {
      __syncthreads();  // SH free (MFMA reads / prev-pass reads done)
      if (wn == p) {
#pragma unroll
        for (int ni = 0; ni < 4; ++ni) {
          int dl = ni * 16 + m16;                 // 0..63
          float bb = bqkv[2048 + dgbase + p * 64 + dl];
#pragma unroll
          for (int mi = 0; mi < 4; ++mi)
#pragma unroll
            for (int r = 0; r < 4; ++r) {
              int sl = wm * 64 + mi * 16 + quad * 4 + r;   // 0..127
              int sls = sl ^ ((dl & 7) << 4);              // bank swizzle
              SH[dl * 128 + sls] = f2bf(acc[mi][ni][r] + bb);
            }
        }
      }
      __syncthreads();
      int dl = tid >> 2;                    // 0..63
      int dg = dgbase + p * 64 + dl;        // global v col 0..1023
      unsigned short* dst =
          vTb + ((size_t)(bat * 16 + (dg >> 6)) * 64 + (dg & 63)) * 2048 + s_base;
#pragma unroll
      for (int i = 0; i < 4; ++i) {
        int s0 = (tid & 3) * 8 + i * 32;
        int s0s = s0 ^ ((dl & 7) << 4);
        *(uint4*)(dst + s0) = *(const uint4*)&SH[dl * 128 + s0s];
      }
    }
  } else {
    int nwin = n0 + wn * 64;
    if (sec <= 1) {
      float qs = (sec == 0) ? QSCALE : 1.0f;
#pragma unroll
      for (int ni = 0; ni < 4; ++ni) {
        int col = nwin + ni * 16 + m16;
        float bb = bqkv[col];
#pragma unroll
        for (int mi = 0; mi < 4; ++mi)
#pragma unroll
          for (int r = 0; r < 4; ++r) {
            int row = m0 + wm * 64 + mi * 16 + quad * 4 + r;
            qkb[(size_t)row * 2048 + col] = f2bf((acc[mi][ni][r] + bb) * qs);
          }
      }
    } else {
#pragma unroll
      for (int ni = 0; ni < 4; ++ni) {
        int col = nwin + ni * 16 + m16;
        int g = col - 3072;
        float bb = bgate[g];
#pragma unroll
        for (int mi = 0; mi < 4; ++mi)
#pragma unroll
          for (int r = 0; r < 4; ++r) {
            int row = m0 + wm * 64 + mi * 16 + quad * 4 + r;
            float v = acc[mi][ni][r] + bb;
            v = v * __builtin_amdgcn_rcpf(1.0f + exp2f(-v * LOG2E));  // SiLU
            ub[(size_t)row * 1024 + g] = f2bf(v);
          }
      }
    }
  }
}

// ---------------------------------------------------------------------------
// Kernel 4: output GEMM: prod[4096,1024] @ wout[1024,1024]^T + b + x -> f32
// ---------------------------------------------------------------------------
__global__ __launch_bounds__(256) void gemm_out(
    const unsigned short* __restrict__ A, const unsigned short* __restrict__ Bt,
    const float* __restrict__ bias, const float* __restrict__ resid,
    float* __restrict__ C) {
  __shared__ unsigned short As[128 * 32];
  __shared__ unsigned short Bs[128 * 32];
  const int K = 1024, N = 1024;
  int tid = threadIdx.x;
  int wave = tid >> 6, lane = tid & 63;
  int quad = lane >> 4, m16 = lane & 15;
  int wm = wave >> 1, wn = wave & 1;
  int m0 = blockIdx.y * 128, n0 = blockIdx.x * 128;
  int lrow = tid >> 2;
  int lcol = (tid & 3) * 8;
  const unsigned short* Ar0 = A + (size_t)(m0 + lrow) * K + lcol;
  const unsigned short* Ar1 = A + (size_t)(m0 + lrow + 64) * K + lcol;
  const unsigned short* Br0 = Bt + (size_t)(n0 + lrow) * K + lcol;
  const unsigned short* Br1 = Bt + (size_t)(n0 + lrow + 64) * K + lcol;

  f32x4 acc[4][4];
#pragma unroll
  for (int i = 0; i < 4; ++i)
#pragma unroll
    for (int j = 0; j < 4; ++j) acc[i][j] = (f32x4){0.f, 0.f, 0.f, 0.f};

  uint4 a0 = *(const uint4*)Ar0;
  uint4 a1 = *(const uint4*)Ar1;
  uint4 b0 = *(const uint4*)Br0;
  uint4 b1 = *(const uint4*)Br1;

  for (int k0 = 0; k0 < K; k0 += 32) {
    __syncthreads();
    *(uint4*)&As[lrow * 32 + lcol] = a0;
    *(uint4*)&As[(lrow + 64) * 32 + lcol] = a1;
    *(uint4*)&Bs[lrow * 32 + lcol] = b0;
    *(uint4*)&Bs[(lrow + 64) * 32 + lcol] = b1;
    __syncthreads();
    if (k0 + 32 < K) {
      a0 = *(const uint4*)(Ar0 + k0 + 32);
      a1 = *(const uint4*)(Ar1 + k0 + 32);
      b0 = *(const uint4*)(Br0 + k0 + 32);
      b1 = *(const uint4*)(Br1 + k0 + 32);
    }
    short8 af[4], bfr[4];
#pragma unroll
    for (int mi = 0; mi < 4; ++mi)
      af[mi] = *(const short8*)&As[(wm * 64 + mi * 16 + m16) * 32 + quad * 8];
#pragma unroll
    for (int ni = 0; ni < 4; ++ni)
      bfr[ni] = *(const short8*)&Bs[(wn * 64 + ni * 16 + m16) * 32 + quad * 8];
#pragma unroll
    for (int mi = 0; mi < 4; ++mi)
#pragma unroll
      for (int ni = 0; ni < 4; ++ni)
        acc[mi][ni] = __builtin_amdgcn_mfma_f32_16x16x32_bf16(
            af[mi], bfr[ni], acc[mi][ni], 0, 0, 0);
  }
#pragma unroll
  for (int ni = 0; ni < 4; ++ni) {
    int col = n0 + wn * 64 + ni * 16 + m16;
    float bb = bias[col];
#pragma unroll
    for (int mi = 0; mi < 4; ++mi)
#pragma unroll
      for (int r = 0; r < 4; ++r) {
        int row = m0 + wm * 64 + mi * 16 + quad * 4 + r;
        C[(size_t)row * N + col] =
            acc[mi][ni][r] + bb + resid[(size_t)row * N + col];
      }
  }
}

// ---------------------------------------------------------------------------
// Kernel 5: MFMA sigmoid attention, causal, paired q-tiles + fused *u.
// Block = (b,h,pair): q-tiles qtA=blockIdx.x (0..15), qtB=31-qtA (33 balanced
// tile-computes). Q held in REGISTERS (A-frag layout, per-wave) — no Qs LDS
// -> 27.6 KB LDS -> ~5 blocks/CU. K/V register-prefetched across k-iters
// (2-barrier staging). Ps columns XOR-swizzled (conflict-free).
// ---------------------------------------------------------------------------
__global__ __launch_bounds__(256) void attn_mfma(
    const unsigned short* __restrict__ qk, const unsigned short* __restrict__ vT,
    const unsigned short* __restrict__ u, const float* __restrict__ rpb,
    unsigned short* __restrict__ prod) {
  __shared__ unsigned short Ks[64 * 72];
  __shared__ unsigned short Vs[64 * 72];   // Vt[d][key]
  __shared__ unsigned short Ps[64 * 72];   // wave-private rows, col-swizzled

  int qtA = blockIdx.x;         // 0..15
  int qtB = 31 - qtA;           // 16..31
  int q0A = qtA * 64, q0B = qtB * 64;
  int bh = blockIdx.y;
  int b = bh >> 4, h = bh & 15;
  int t = threadIdx.x;
  int wave = t >> 6, lane = t & 63;
  int quad = lane >> 4, m16 = lane & 15;

  const unsigned short* qbase = qk + (size_t)(b * SS) * 2048 + h * 64;
  const unsigned short* kbase = qbase + 1024;
  const unsigned short* vbase = vT + (size_t)bh * 64 * 2048;

  int row = t >> 3, blk8 = (t & 7) * 8;  // staging coords (32 rows x 64 cols)

  // Q fragments in registers (A-frag layout: lane m16 = q-row, cols quad*8+)
  short8 qfA[2], qfB[2];
#pragma unroll
  for (int s = 0; s < 2; ++s) {
    qfA[s] = *(const short8*)(qbase + (size_t)(q0A + wave * 16 + m16) * 2048 + s * 32 + quad * 8);
    qfB[s] = *(const short8*)(qbase + (size_t)(q0B + wave * 16 + m16) * 2048 + s * 32 + quad * 8);
  }

  f32x4 zero4 = {0.f, 0.f, 0.f, 0.f};
  f32x4 caccA[4], caccB[4];
#pragma unroll
  for (int nb = 0; nb < 4; ++nb) { caccA[nb] = zero4; caccB[nb] = zero4; }

  float hb2 = rpb[h] * LOG2E;
  float cexp = exp2f(-hb2);             // p = rcp(1 + cexp * 2^-s)
  int ktmax = qtB;
  int psw = quad << 3;                  // Ps write swizzle key
  int psr = ((m16 >> 2) & 3) << 3;      // Ps read un-swizzle key

  // preload kt=0 K/V into regs
  uint4 kv0, kv1, vv0, vv1;
  {
    const unsigned short* kp = kbase + (size_t)row * 2048 + blk8;
    const unsigned short* vp = vbase + (size_t)row * 2048 + blk8;
    kv0 = *(const uint4*)kp;
    kv1 = *(const uint4*)(kp + (size_t)32 * 2048);
    vv0 = *(const uint4*)vp;
    vv1 = *(const uint4*)(vp + (size_t)32 * 2048);
  }

  for (int kt = 0; kt <= ktmax; ++kt) {
    int k0 = kt * 64;
    __syncthreads();  // prev-iter readers of Ks/Vs done
    *(uint4*)&Ks[row * 72 + blk8] = kv0;
    *(uint4*)&Ks[(row + 32) * 72 + blk8] = kv1;
    *(uint4*)&Vs[row * 72 + blk8] = vv0;
    *(uint4*)&Vs[(row + 32) * 72 + blk8] = vv1;
    __syncthreads();
    if (kt < ktmax) {  // prefetch kt+1; latency overlaps compute below
      int k0n = k0 + 64;
      const unsigned short* kp = kbase + (size_t)(k0n + row) * 2048 + blk8;
      const unsigned short* vp = vbase + (size_t)row * 2048 + k0n + blk8;
      kv0 = *(const uint4*)kp;
      kv1 = *(const uint4*)(kp + (size_t)32 * 2048);
      vv0 = *(const uint4*)vp;
      vv1 = *(const uint4*)(vp + (size_t)32 * 2048);
    }

#pragma unroll
    for (int tile = 0; tile < 2; ++tile) {
      if (tile == 1 && kt > qtA) break;
      const short8* qf = (tile == 0) ? qfB : qfA;
      int q0 = (tile == 0) ? q0B : q0A;
      bool diag = (tile == 0) ? (kt == qtB) : (kt == qtA);
      f32x4* cacc = (tile == 0) ? caccB : caccA;

      f32x4 sacc[4];
#pragma unroll
      for (int nb = 0; nb < 4; ++nb) sacc[nb] = zero4;
#pragma unroll
      for (int s = 0; s < 2; ++s) {
#pragma unroll
        for (int nb = 0; nb < 4; ++nb) {
          short8 bf = *(const short8*)&Ks[(nb * 16 + m16) * 72 + s * 32 + quad * 8];
          sacc[nb] = __builtin_amdgcn_mfma_f32_16x16x32_bf16(qf[s], bf, sacc[nb], 0, 0, 0);
        }
      }
#pragma unroll
      for (int nb = 0; nb < 4; ++nb) {
#pragma unroll
        for (int r = 0; r < 4; ++r) {
          float e = exp2f(-sacc[nb][r]);
          float p = __builtin_amdgcn_rcpf(fmaf(cexp, e, 1.0f));
          if (diag) {
            int key = k0 + nb * 16 + m16;
            int q = q0 + wave * 16 + quad * 4 + r;
            if (key > q) p = 0.f;
          }
          int colS = (nb * 16 + m16) ^ psw;  // conflict-free bank swizzle
          Ps[(wave * 16 + quad * 4 + r) * 72 + colS] = f2bf_fast(p);
        }
      }
      // no barrier: wave reads only its own Ps rows (in-wave LDS ordering)
#pragma unroll
      for (int s = 0; s < 2; ++s) {
        int pcol = (s * 32 + quad * 8) ^ psr;  // un-swizzle (8-contig)
        short8 a = *(const short8*)&Ps[(wave * 16 + m16) * 72 + pcol];
#pragma unroll
        for (int nb = 0; nb < 4; ++nb) {
          short8 bf = *(const short8*)&Vs[(nb * 16 + m16) * 72 + s * 32 + quad * 8];
          cacc[nb] = __builtin_amdgcn_mfma_f32_16x16x32_bf16(a, bf, cacc[nb], 0, 0, 0);
        }
      }
    }
  }

  // epilogue: prod = bf16(ctx * u), layout [token][h*64+d], both tiles
  const unsigned short* ub_ = u + (size_t)(b * SS) * 1024 + h * 64;
  unsigned short* pb_ = prod + (size_t)(b * SS) * 1024 + h * 64;
#pragma unroll
  for (int nb = 0; nb < 4; ++nb) {
    int d = nb * 16 + m16;
#pragma unroll
    for (int r = 0; r < 4; ++r) {
      int qA = q0A + wave * 16 + quad * 4 + r;
      int qB = q0B + wave * 16 + quad * 4 + r;
      pb_[(size_t)qA * 1024 + d] = f2bf(caccA[nb][r] * bf2f(ub_[(size_t)qA * 1024 + d]));
      pb_[(size_t)qB * 1024 + d] = f2bf(caccB[nb][r] * bf2f(ub_[(size_t)qB * 1024 + d]));
    }
  }
}

// ---------------------------------------------------------------------------
extern "C" void kernel_launch(void* const* d_in, const int* in_sizes, int n_in,
                              void* d_out, int out_size, void* d_ws, size_t ws_size,
                              hipStream_t stream) {
  const float* x      = (const float*)d_in[0];
  // d_in[1] = attention_mask (causal tril) — computed analytically, not read
  const float* gamma  = (const float*)d_in[2];
  const float* beta   = (const float*)d_in[3];
  const float* w_qkv  = (const float*)d_in[4];
  const float* b_qkv  = (const float*)d_in[5];
  const float* w_gate = (const float*)d_in[6];
  const float* b_gate = (const float*)d_in[7];
  const float* w_out  = (const float*)d_in[8];
  const float* b_out  = (const float*)d_in[9];
  const float* rpb    = (const float*)d_in[10];
  float* out = (float*)d_out;

  unsigned short* xnb   = (unsigned short*)d_ws;  // 4096*1024
  unsigned short* qkb   = xnb + 4194304;          // 4096*2048 (q|k)
  unsigned short* vTb   = qkb + 8388608;          // 32*64*2048
  unsigned short* ub    = vTb + 4194304;          // 4096*1024
  unsigned short* prodb = ub + 4194304;           // 4096*1024
  unsigned short* wcatT = prodb + 4194304;        // 4096*1024 (qkv|gate rows)
  unsigned short* woutT = wcatT + 4194304;        // 1024*1024
  // total ~60 MB

  // 1. LayerNorm -> bf16
  ln_kernel<<<BB * SS, 256, 0, stream>>>(x, gamma, beta, xnb);
  // 2. Merged weight transposes fp32[K][N] -> bf16[N][K]
  wtrans_all<<<dim3(160, 32), 256, 0, stream>>>(w_qkv, w_gate, w_out, wcatT, woutT);
  // 3. Fused QKV+gate GEMM: N=4096 sections -> qkb, vTb (coalesced), ub
  gemm_qkvg<<<dim3(4096 / 128, 4096 / 128), 256, 0, stream>>>(
      xnb, wcatT, b_qkv, b_gate, qkb, vTb, ub);
  // 4. MFMA sigmoid attention (paired q-tiles, Q-in-regs, K/V prefetch)
  attn_mfma<<<dim3(16, BB * HH), 256, 0, stream>>>(qkb, vTb, ub, rpb, prodb);
  // 5. Output projection: prod @ w_out + b_out + x -> f32 out
  gemm_out<<<dim3(1024 / 128, 4096 / 128), 256, 0, stream>>>(
      prodb, woutT, b_out, x, out);
}